// Round 9
// baseline (405.074 us; speedup 1.0000x reference)
//
#include <hip/hip_runtime.h>
#include <cmath>

#define NB 4
#define NC 128
#define NH 128
#define NW 128
#define HD 64
#define WD 64
#define NL 4096      // 64*64 positions / patches
#define NPIX 16384   // 128*128 output pixels per batch
#define SM_SCALE 2550.0f
#define CUT 40.0f
#define CUTS 0.216f  // candidate margin in score units
#define MAXENT 8
#define MAXC 256
#define PLMAX 32     // 4 positions x MAXENT survivors

struct Ent { int l; float p; };

typedef __attribute__((ext_vector_type(4))) float f32x4;
typedef __attribute__((ext_vector_type(8))) short s16x8;

__device__ __forceinline__ unsigned short f2bf(float x) {
  unsigned u = __float_as_uint(x);
  return (unsigned short)((u + 0x7fffu + ((u >> 16) & 1u)) >> 16);
}
__device__ __forceinline__ float bf2f(unsigned short h) {
  return __uint_as_float(((unsigned)h) << 16);
}
__device__ __forceinline__ void gload_lds16(const void* g, void* l) {
  __builtin_amdgcn_global_load_lds(
      (const __attribute__((address_space(1))) void*)g,
      (__attribute__((address_space(3))) void*)l, 16, 0, 0);
}

// ---------- prep ----------
__global__ void k_prep(const float* __restrict__ f, const float* __restrict__ b,
                       float* __restrict__ fd, float* __restrict__ bd) {
  int i = blockIdx.x * blockDim.x + threadIdx.x;
  if (i >= NB*NC*HD*WD) return;
  int x = i & 63, y = (i >> 6) & 63, c = (i >> 12) & 127, bb = i >> 19;
  int src = ((bb*NC + c)*NH + 2*y)*NW + 2*x;
  fd[i] = f[src];
  bd[i] = b[src];
}

__global__ void k_sq(const float* __restrict__ bd, double* __restrict__ sq) {
  int i = blockIdx.x * blockDim.x + threadIdx.x;
  if (i >= NB*HD*WD) return;
  int x = i & 63, y = (i >> 6) & 63, bb = i >> 12;
  double s = 0.0;
  const float* p = bd + (size_t)bb*NC*HD*WD + y*WD + x;
  for (int c = 0; c < NC; ++c) {
    double v = (double)p[(size_t)c*HD*WD];
    s += v*v;
  }
  sq[i] = s;
}

__global__ void k_normmm(const double* __restrict__ sq, const float* __restrict__ mask,
                         float* __restrict__ norm, float* __restrict__ mmv,
                         int* __restrict__ zb) {
  int i = blockIdx.x * blockDim.x + threadIdx.x;
  if (i >= NB*NL) return;
  int pw = i & 63, ph = (i >> 6) & 63, bb = i >> 12;
  double s = 0.0;
  for (int dh = -1; dh <= 1; ++dh) {
    int y = ph + dh; if ((unsigned)y >= 64u) continue;
    for (int dw = -1; dw <= 1; ++dw) {
      int x = pw + dw; if ((unsigned)x >= 64u) continue;
      s += sq[(bb*HD + y)*WD + x];
    }
  }
  norm[i] = (float)sqrt(s);
  float ms = 0.f;
  const float* mb = mask + (size_t)bb*512*512;
  for (int dh = -1; dh <= 1; ++dh) {
    int y = ph + dh; if ((unsigned)y >= 64u) continue;
    for (int dw = -1; dw <= 1; ++dw) {
      int x = pw + dw; if ((unsigned)x >= 64u) continue;
      ms += mb[(y*8)*512 + x*8];
    }
  }
  float m = (ms == 0.f) ? 1.f : 0.f;
  mmv[i] = m;
  if (m == 0.f) atomicAdd(&zb[bb], 1);
}

// ---------- transpose b to pixel-major b_t[bb][pix][c] (for gather) ----------
__global__ __launch_bounds__(256) void k_btrans(const float* __restrict__ b,
                                                float* __restrict__ bt) {
  __shared__ float tile[32][33];
  int bb = blockIdx.z;
  int c0 = blockIdx.y * 32;
  int p0 = blockIdx.x * 32;
  int tx = threadIdx.x & 31, ty = threadIdx.x >> 5;
  const float* bp = b + (size_t)bb*NC*NPIX;
  #pragma unroll
  for (int r = 0; r < 32; r += 8)
    tile[r + ty][tx] = bp[(size_t)(c0 + r + ty)*NPIX + p0 + tx];
  __syncthreads();
  float* btp = bt + (size_t)bb*NPIX*NC;
  #pragma unroll
  for (int r = 0; r < 32; r += 8)
    btp[(size_t)(p0 + r + ty)*NC + c0 + tx] = tile[tx][r + ty];
}

// ---------- transpose fd,bd to pixel-major: bf16 (GEMM) + fp32 (rescore) ----------
__global__ __launch_bounds__(256) void k_fbtrans(const float* __restrict__ fd,
    const float* __restrict__ bd, unsigned short* __restrict__ fdt,
    unsigned short* __restrict__ bdt, float* __restrict__ fdp,
    float* __restrict__ bdp) {
  __shared__ float tf[32][33], tb[32][33];
  int bb = blockIdx.z;
  int c0 = blockIdx.y * 32;
  int p0 = blockIdx.x * 32;
  int tx = threadIdx.x & 31, ty = threadIdx.x >> 5;
  const float* fp = fd + (size_t)bb*NC*NL;
  const float* bp = bd + (size_t)bb*NC*NL;
  #pragma unroll
  for (int r = 0; r < 32; r += 8) {
    tf[r + ty][tx] = fp[(size_t)(c0 + r + ty)*NL + p0 + tx];
    tb[r + ty][tx] = bp[(size_t)(c0 + r + ty)*NL + p0 + tx];
  }
  __syncthreads();
  #pragma unroll
  for (int r = 0; r < 32; r += 8) {
    float fv = tf[tx][r + ty];
    float bv = tb[tx][r + ty];
    size_t idx = ((size_t)bb*NL + p0 + r + ty)*NC + c0 + tx;
    fdt[idx] = f2bf(fv);
    bdt[idx] = f2bf(bv);
    fdp[idx] = fv;
    bdp[idx] = bv;
  }
}

// ---------- pixel-dot GEMM: D[p][l] = bf16(<fd_pix(p), bd_pix(l)>), K=128 ----------
__global__ __launch_bounds__(256) void k_gemmD(
    const unsigned short* __restrict__ A, const unsigned short* __restrict__ B,
    unsigned short* __restrict__ D) {
  __shared__ __align__(16) unsigned short As[128*32];
  __shared__ __align__(16) unsigned short Bs[128*32];
  int t = threadIdx.x;
  int w = t >> 6, l = t & 63;
  int by = blockIdx.y, bx = blockIdx.x;
  int wr = w >> 1, wc = w & 1;
  f32x4 acc[4][4] = {};
  int aoff[4], boff[4];
  #pragma unroll
  for (int m = 0; m < 4; ++m) {
    aoff[m] = ((wr*64 + m*16 + (l & 15)) * 32 + ((l >> 4) * 8)) * 2;
    boff[m] = ((wc*64 + m*16 + (l & 15)) * 32 + ((l >> 4) * 8)) * 2;
  }
  const char* Ab = (const char*)A;
  const char* Bb = (const char*)B;
  char* AsB = (char*)As;
  char* BsB = (char*)Bs;
  int off = (w*2) * 1024 + l * 16;
  int r0 = off >> 6, cb0 = off & 63;
  int off1 = off + 1024;
  int r1 = off1 >> 6, cb1 = off1 & 63;
  for (int k0 = 0; k0 < 128; k0 += 32) {
    gload_lds16(Ab + ((size_t)(by*128 + r0) * 128 + k0) * 2 + cb0, AsB + (w*2+0)*1024);
    gload_lds16(Ab + ((size_t)(by*128 + r1) * 128 + k0) * 2 + cb1, AsB + (w*2+1)*1024);
    gload_lds16(Bb + ((size_t)(bx*128 + r0) * 128 + k0) * 2 + cb0, BsB + (w*2+0)*1024);
    gload_lds16(Bb + ((size_t)(bx*128 + r1) * 128 + k0) * 2 + cb1, BsB + (w*2+1)*1024);
    __syncthreads();
    s16x8 af[4], bf[4];
    #pragma unroll
    for (int m = 0; m < 4; ++m) af[m] = *(const s16x8*)(AsB + aoff[m]);
    #pragma unroll
    for (int n = 0; n < 4; ++n) bf[n] = *(const s16x8*)(BsB + boff[n]);
    #pragma unroll
    for (int m = 0; m < 4; ++m)
      #pragma unroll
      for (int n = 0; n < 4; ++n)
        acc[m][n] = __builtin_amdgcn_mfma_f32_16x16x32_bf16(af[m], bf[n], acc[m][n], 0, 0, 0);
    __syncthreads();
  }
  int cr = l >> 4;
  int cc = l & 15;
  #pragma unroll
  for (int n = 0; n < 4; ++n) {
    int col = bx*128 + wc*64 + n*16 + cc;
    #pragma unroll
    for (int m = 0; m < 4; ++m) {
      int grow = by*128 + wr*64 + m*16 + cr*4;
      #pragma unroll
      for (int j = 0; j < 4; ++j)
        D[(size_t)(grow + j) * NL + col] = f2bf(acc[m][n][j]);
    }
  }
}

// ---------- horizontal pass: E[p][l] = sum_dw D[p+dw][l+dw], register-shifted ----------
__global__ __launch_bounds__(256) void k_hpass(const unsigned short* __restrict__ D,
                                               unsigned short* __restrict__ E) {
  int p = blockIdx.x;
  int px = p & 63;
  int t = threadIdx.x;
  bool okm = px > 0, okp = px < 63;
  const unsigned short* r0 = D + (size_t)p*NL;
  const unsigned short* rm = D + (size_t)(okm ? p-1 : p)*NL;
  const unsigned short* rp = D + (size_t)(okp ? p+1 : p)*NL;
  #pragma unroll
  for (int ch = 0; ch < 2; ++ch) {
    int l0 = (ch*256 + t) * 8;
    uint4 b0 = *(const uint4*)(r0 + l0);
    int lam = l0 ? (l0 - 8) : 0;
    uint4 am = *(const uint4*)(rm + lam);
    uint4 bm = *(const uint4*)(rm + l0);
    uint4 bp = *(const uint4*)(rp + l0);
    int lcp = (l0 < NL - 8) ? (l0 + 8) : l0;
    uint4 cp = *(const uint4*)(rp + lcp);
    unsigned bmu[4] = {bm.x, bm.y, bm.z, bm.w};
    unsigned bpu[4] = {bp.x, bp.y, bp.z, bp.w};
    unsigned b0u[4] = {b0.x, b0.y, b0.z, b0.w};
    unsigned sm[4], sp[4];
    sm[0] = (am.w >> 16) | (bmu[0] << 16);
    sm[1] = (bmu[0] >> 16) | (bmu[1] << 16);
    sm[2] = (bmu[1] >> 16) | (bmu[2] << 16);
    sm[3] = (bmu[2] >> 16) | (bmu[3] << 16);
    sp[0] = (bpu[0] >> 16) | (bpu[1] << 16);
    sp[1] = (bpu[1] >> 16) | (bpu[2] << 16);
    sp[2] = (bpu[2] >> 16) | (bpu[3] << 16);
    sp[3] = (bpu[3] >> 16) | (cp.x << 16);
    unsigned eo[4];
    #pragma unroll
    for (int k = 0; k < 4; ++k) {
      int j0 = 2*k;
      int lx0 = (l0 + j0) & 63;
      float v0 = (okm && lx0 > 0) ? bf2f((unsigned short)(sm[k] & 0xffffu)) : 0.f;
      v0 += bf2f((unsigned short)(b0u[k] & 0xffffu));
      v0 += (okp && lx0 < 63) ? bf2f((unsigned short)(sp[k] & 0xffffu)) : 0.f;
      int lx1 = (l0 + j0 + 1) & 63;
      float v1 = (okm && lx1 > 0) ? bf2f((unsigned short)(sm[k] >> 16)) : 0.f;
      v1 += bf2f((unsigned short)(b0u[k] >> 16));
      v1 += (okp && lx1 < 63) ? bf2f((unsigned short)(sp[k] >> 16)) : 0.f;
      eo[k] = (unsigned)f2bf(v0) | ((unsigned)f2bf(v1) << 16);
    }
    uint4 outv; outv.x = eo[0]; outv.y = eo[1]; outv.z = eo[2]; outv.w = eo[3];
    *(uint4*)(E + (size_t)p*NL + l0) = outv;
  }
}

// ---------- fused vertical stencil + rowmax + scan + exact rescore ----------
// fpat layout [r][c] (values identical to k=c*9+r); fdp/bdp pixel-major fp32.
__global__ __launch_bounds__(256) void k_rescore3(const unsigned short* __restrict__ E,
    const float* __restrict__ mmv, const float* __restrict__ fdp,
    const float* __restrict__ bdp, const float* __restrict__ nrm,
    const int* __restrict__ zb, int* __restrict__ cnt, Ent* __restrict__ ent,
    float* __restrict__ ooff, int bb) {
  int p = blockIdx.x, t = threadIdx.x;
  int wid = t >> 6, lane = t & 63;
  int ihp = p >> 6, iwp = p & 63;
  int py = p >> 6;
  __shared__ float fpat[1152];    // [r][c]
  __shared__ int cl[MAXC];
  __shared__ float cs[MAXC];
  __shared__ float rmx[256];
  __shared__ int cnt_s;
  if (t == 0) cnt_s = 0;
  const float* fdpb = fdp + (size_t)bb*NL*NC;
  const float* bdpb = bdp + (size_t)bb*NL*NC;
  // coalesced fpat staging: 9 rows of 128 consecutive floats
  #pragma unroll
  for (int pass = 0; pass < 5; ++pass) {
    int idx = pass*256 + t;
    if (idx < 1152) {
      int r = idx >> 7, c = idx & 127;
      int y = ihp + r/3 - 1, x = iwp + (r % 3) - 1;
      fpat[idx] = (((unsigned)y < 64u) && ((unsigned)x < 64u))
                  ? fdpb[(size_t)(y*WD + x)*NC + c] : 0.f;
    }
  }

  // vertical 3-tap over E: s[i] for l = t*16 + i
  float sv[16], mv[16];
  const float* mb = mmv + bb*NL;
  #pragma unroll
  for (int ch = 0; ch < 2; ++ch) {
    int l0 = t*16 + ch*8;
    int ly = l0 >> 6;
    bool okm = (py > 0) && (ly > 0);
    bool okp = (py < 63) && (ly < 63);
    size_t a0 = (size_t)p*NL + l0;
    size_t am = okm ? ((size_t)(p-64)*NL + (l0-64)) : a0;
    size_t ap = okp ? ((size_t)(p+64)*NL + (l0+64)) : a0;
    uint4 e0 = *(const uint4*)(E + a0);
    uint4 em = *(const uint4*)(E + am);
    uint4 ep = *(const uint4*)(E + ap);
    unsigned e0u[4] = {e0.x,e0.y,e0.z,e0.w};
    unsigned emu[4] = {em.x,em.y,em.z,em.w};
    unsigned epu[4] = {ep.x,ep.y,ep.z,ep.w};
    #pragma unroll
    for (int k = 0; k < 4; ++k) {
      float v0 = okm ? bf2f((unsigned short)(emu[k] & 0xffffu)) : 0.f;
      v0 += bf2f((unsigned short)(e0u[k] & 0xffffu));
      v0 += okp ? bf2f((unsigned short)(epu[k] & 0xffffu)) : 0.f;
      float v1 = okm ? bf2f((unsigned short)(emu[k] >> 16)) : 0.f;
      v1 += bf2f((unsigned short)(e0u[k] >> 16));
      v1 += okp ? bf2f((unsigned short)(epu[k] >> 16)) : 0.f;
      int i0 = ch*8 + 2*k;
      int l = l0 + 2*k;
      float rn0 = 1.f / fmaxf(nrm[bb*NL + l], 1e-4f);
      float rn1 = 1.f / fmaxf(nrm[bb*NL + l + 1], 1e-4f);
      sv[i0]   = v0 * rn0;
      sv[i0+1] = v1 * rn1;
      mv[i0]   = mb[l];
      mv[i0+1] = mb[l + 1];
    }
  }
  float mx = -3e38f;
  #pragma unroll
  for (int i = 0; i < 16; ++i)
    if (mv[i] != 0.f) mx = fmaxf(mx, sv[i]);
  rmx[t] = mx;
  __syncthreads();
  for (int o = 128; o > 0; o >>= 1) {
    if (t < o) rmx[t] = fmaxf(rmx[t], rmx[t+o]);
    __syncthreads();
  }
  float thr = rmx[0] - CUTS;
  #pragma unroll
  for (int i = 0; i < 16; ++i) {
    if (mv[i] != 0.f && sv[i] >= thr) {
      int slot = atomicAdd(&cnt_s, 1);
      if (slot < MAXC) cl[slot] = t*16 + i;
    }
  }
  __syncthreads();
  int nc = cnt_s < MAXC ? cnt_s : MAXC;
  if (t == 0 && nc > 1) {        // deterministic order: sort candidates by l
    for (int a = 1; a < nc; ++a) {
      int v = cl[a]; int q = a - 1;
      while (q >= 0 && cl[q] > v) { cl[q+1] = cl[q]; --q; }
      cl[q+1] = v;
    }
  }
  __syncthreads();
  for (int a = wid; a < nc; a += 4) {
    int lidx = cl[a]; int ph = lidx >> 6, pw = lidx & 63;
    float sum = 0.f;
    #pragma unroll
    for (int kk = 0; kk < 18; ++kk) {     // 1152 = 18*64; same k->lane map as round 2
      int k = kk*64 + lane;
      int c = k / 9, r = k % 9;
      int y = ph + r/3 - 1, x = pw + (r % 3) - 1;
      float bv = (((unsigned)y < 64u) && ((unsigned)x < 64u))
                 ? bdpb[(size_t)(y*WD + x)*NC + c] : 0.f;
      sum = fmaf(fpat[r*128 + c], bv, sum);
    }
    #pragma unroll
    for (int o = 32; o > 0; o >>= 1) sum += __shfl_xor(sum, o, 64);
    if (lane == 0) cs[a] = sum / fmaxf(nrm[bb*NL + lidx], 1e-4f);
  }
  __syncthreads();
  if (t == 0) {
    float smax = -3e38f; int sidx = 0x7fffffff;
    for (int a = 0; a < nc; ++a)
      if (cs[a] > smax) { smax = cs[a]; sidx = cl[a]; }   // sorted by l
    int Z = zb[bb];
    size_t base = (size_t)(bb*NL + p) * MAXENT;
    if (nc == 0) {
      cnt[bb*NL + p] = 0;
      ooff[((bb*2 + 0)*HD + ihp)*WD + iwp] = (float)(0 - ihp);
      ooff[((bb*2 + 1)*HD + ihp)*WD + iwp] = (float)(0 - iwp);
    } else {
      float xm = smax * SM_SCALE;
      if (Z > 0) xm = fmaxf(xm, 0.f);
      float den = 0.f;
      for (int a = 0; a < nc; ++a) {
        float d = cs[a] * SM_SCALE - xm;
        if (d > -CUT) den += expf(d);
      }
      if (Z > 0 && -xm > -CUT) den += (float)Z * expf(-xm);
      int n = 0;
      for (int a = 0; a < nc && n < MAXENT; ++a) {
        float d = cs[a] * SM_SCALE - xm;
        if (d > -CUT) { ent[base + n].l = cl[a]; ent[base + n].p = expf(d) / den; ++n; }
      }
      cnt[bb*NL + p] = n;
      ooff[((bb*2 + 0)*HD + ihp)*WD + iwp] = (float)((sidx >> 6) - ihp);
      ooff[((bb*2 + 1)*HD + ihp)*WD + iwp] = (float)((sidx & 63) - iwp);
    }
  }
}

// ---------- plan: per output pixel, channel-independent contribution list ----------
__global__ void k_plan(const int* __restrict__ cnt, const Ent* __restrict__ ent,
                       int* __restrict__ npl, int* __restrict__ offs,
                       float* __restrict__ wts) {
  int i = blockIdx.x * blockDim.x + threadIdx.x;
  if (i >= NB*NPIX) return;
  int pix = i & (NPIX-1); int bb = i >> 14;
  int oh = pix >> 7, ow = pix & 127;
  int ihlo = (oh - 1) >> 1;
  int iwlo = (ow - 1) >> 1;
  int n = 0;
  #pragma unroll
  for (int a = 0; a < 2; ++a) {
    int ih = ihlo + a;
    if ((unsigned)ih >= 64u) continue;
    #pragma unroll
    for (int d = 0; d < 2; ++d) {
      int iw = iwlo + d;
      if ((unsigned)iw >= 64u) continue;
      int pidx = bb*NL + ih*WD + iw;
      int nn = cnt[pidx];
      const Ent* ep = ent + (size_t)pidx*MAXENT;
      for (int j = 0; j < nn; ++j) {
        Ent e = ep[j];
        int ph = e.l >> 6, pw = e.l & 63;
        int yy = oh + 2*(ph - ih);
        int xx = ow + 2*(pw - iw);
        if ((unsigned)yy < 128u && (unsigned)xx < 128u) {
          offs[((size_t)bb*PLMAX + n)*NPIX + pix] = yy*NW + xx;
          wts[((size_t)bb*PLMAX + n)*NPIX + pix] = e.p;
          ++n;
        }
      }
    }
  }
  npl[i] = n;
}

// ---------- gather v4: thread = (pixel, channel-quad), pixel-major bt ----------
__global__ __launch_bounds__(256) void k_gather4(const float* __restrict__ bt,
    const int* __restrict__ npl, const int* __restrict__ offs,
    const float* __restrict__ wts, float* __restrict__ yout) {
  __shared__ float sm[8][132];
  int bb = blockIdx.y;
  int pixbase = blockIdx.x * 8;
  int t = threadIdx.x;
  int g = t & 31, pl = t >> 5;
  int c0 = g * 4;
  int pix = pixbase + pl;
  const float* btb = bt + (size_t)bb*NPIX*NC;
  int n = npl[bb*NPIX + pix];
  float ax = 0.f, ay = 0.f, az = 0.f, aw = 0.f;
  for (int j = 0; j < n; ++j) {
    int off = offs[((size_t)bb*PLMAX + j)*NPIX + pix];
    float wv = wts[((size_t)bb*PLMAX + j)*NPIX + pix];
    float4 v = *(const float4*)(btb + (size_t)off*NC + c0);
    ax = fmaf(wv, v.x, ax); ay = fmaf(wv, v.y, ay);
    az = fmaf(wv, v.z, az); aw = fmaf(wv, v.w, aw);
  }
  sm[pl][c0+0] = ax; sm[pl][c0+1] = ay; sm[pl][c0+2] = az; sm[pl][c0+3] = aw;
  __syncthreads();
  #pragma unroll
  for (int k = 0; k < 4; ++k) {
    int c = (t >> 3) + 32*k;
    int i = t & 7;
    yout[((size_t)bb*NC + c)*NPIX + pixbase + i] = sm[i][c] * 0.25f;
  }
}

extern "C" void kernel_launch(void* const* d_in, const int* in_sizes, int n_in,
                              void* d_out, int out_size, void* d_ws, size_t ws_size,
                              hipStream_t stream) {
  const float* f = (const float*)d_in[0];
  const float* b = (const float*)d_in[1];
  const float* mask = (const float*)d_in[2];
  float* out = (float*)d_out;

  char* w = (char*)d_ws;
  float* fd   = (float*)w;  w += (size_t)NB*NC*HD*WD*4;
  float* bd   = (float*)w;  w += (size_t)NB*NC*HD*WD*4;
  double* sq  = (double*)w; w += (size_t)NB*HD*WD*8;
  float* norm = (float*)w;  w += (size_t)NB*NL*4;
  float* mmv  = (float*)w;  w += (size_t)NB*NL*4;
  int* cnt    = (int*)w;    w += (size_t)NB*NL*4;
  Ent* ent    = (Ent*)w;    w += (size_t)NB*NL*MAXENT*sizeof(Ent);
  unsigned short* fdt = (unsigned short*)w; w += (size_t)NB*NL*NC*2;
  unsigned short* bdt = (unsigned short*)w; w += (size_t)NB*NL*NC*2;
  float* fdp  = (float*)w;  w += (size_t)NB*NL*NC*4;
  float* bdp  = (float*)w;  w += (size_t)NB*NL*NC*4;
  int* zb     = (int*)w;    w += 64;
  int* npl    = (int*)w;    w += (size_t)NB*NPIX*4;
  int* offs   = (int*)w;    w += (size_t)NB*PLMAX*NPIX*4;
  float* wts  = (float*)w;  w += (size_t)NB*PLMAX*NPIX*4;
  // D (32 MB, in-loop) aliases bt (33.5 MB, post-loop)
  float* bt   = (float*)w;
  unsigned short* D = (unsigned short*)w; w += (size_t)NB*NPIX*NC*4;
  unsigned short* E = (unsigned short*)w;   // 32 MB, reused per batch

  int n1 = NB*NC*HD*WD;
  k_prep<<<(n1+255)/256, 256, 0, stream>>>(f, b, fd, bd);
  k_sq<<<(NB*HD*WD+255)/256, 256, 0, stream>>>(bd, sq);
  hipMemsetAsync(zb, 0, 64, stream);
  k_normmm<<<(NB*NL+255)/256, 256, 0, stream>>>(sq, mask, norm, mmv, zb);
  k_fbtrans<<<dim3(NL/32, NC/32, NB), 256, 0, stream>>>(fd, bd, fdt, bdt, fdp, bdp);

  float* ooff = out + (size_t)NB*NC*NH*NW;
  for (int bb = 0; bb < NB; ++bb) {
    k_gemmD<<<dim3(32, 32), 256, 0, stream>>>(fdt + (size_t)bb*NL*NC,
                                              bdt + (size_t)bb*NL*NC, D);
    k_hpass<<<NL, 256, 0, stream>>>(D, E);
    k_rescore3<<<NL, 256, 0, stream>>>(E, mmv, fdp, bdp, norm, zb, cnt, ent, ooff, bb);
  }
  k_btrans<<<dim3(NPIX/32, NC/32, NB), 256, 0, stream>>>(b, bt);
  k_plan<<<(NB*NPIX+255)/256, 256, 0, stream>>>(cnt, ent, npl, offs, wts);
  k_gather4<<<dim3(NPIX/8, NB), 256, 0, stream>>>(bt, npl, offs, wts, out);
}

// Round 10
// 384.685 us; speedup vs baseline: 1.0530x; 1.0530x over previous
//
#include <hip/hip_runtime.h>
#include <cmath>

#define NB 4
#define NC 128
#define NH 128
#define NW 128
#define HD 64
#define WD 64
#define NL 4096      // 64*64 positions / patches
#define NPIX 16384   // 128*128 output pixels per batch
#define SM_SCALE 2550.0f
#define CUT 40.0f
#define CUTS 0.216f  // candidate margin in score units
#define MAXENT 8
#define MAXC 256
#define PLMAX 32     // 4 positions x MAXENT survivors

struct Ent { int l; float p; };

typedef __attribute__((ext_vector_type(4))) float f32x4;
typedef __attribute__((ext_vector_type(8))) short s16x8;

__device__ __forceinline__ unsigned short f2bf(float x) {
  unsigned u = __float_as_uint(x);
  return (unsigned short)((u + 0x7fffu + ((u >> 16) & 1u)) >> 16);
}
__device__ __forceinline__ float bf2f(unsigned short h) {
  return __uint_as_float(((unsigned)h) << 16);
}
__device__ __forceinline__ void gload_lds16(const void* g, void* l) {
  __builtin_amdgcn_global_load_lds(
      (const __attribute__((address_space(1))) void*)g,
      (__attribute__((address_space(3))) void*)l, 16, 0, 0);
}

// ---------- prep ----------
__global__ void k_prep(const float* __restrict__ f, const float* __restrict__ b,
                       float* __restrict__ fd, float* __restrict__ bd) {
  int i = blockIdx.x * blockDim.x + threadIdx.x;
  if (i >= NB*NC*HD*WD) return;
  int x = i & 63, y = (i >> 6) & 63, c = (i >> 12) & 127, bb = i >> 19;
  int src = ((bb*NC + c)*NH + 2*y)*NW + 2*x;
  fd[i] = f[src];
  bd[i] = b[src];
}

__global__ void k_sq(const float* __restrict__ bd, double* __restrict__ sq) {
  int i = blockIdx.x * blockDim.x + threadIdx.x;
  if (i >= NB*HD*WD) return;
  int x = i & 63, y = (i >> 6) & 63, bb = i >> 12;
  double s = 0.0;
  const float* p = bd + (size_t)bb*NC*HD*WD + y*WD + x;
  for (int c = 0; c < NC; ++c) {
    double v = (double)p[(size_t)c*HD*WD];
    s += v*v;
  }
  sq[i] = s;
}

__global__ void k_normmm(const double* __restrict__ sq, const float* __restrict__ mask,
                         float* __restrict__ norm, float* __restrict__ mmv,
                         int* __restrict__ zb) {
  int i = blockIdx.x * blockDim.x + threadIdx.x;
  if (i >= NB*NL) return;
  int pw = i & 63, ph = (i >> 6) & 63, bb = i >> 12;
  double s = 0.0;
  for (int dh = -1; dh <= 1; ++dh) {
    int y = ph + dh; if ((unsigned)y >= 64u) continue;
    for (int dw = -1; dw <= 1; ++dw) {
      int x = pw + dw; if ((unsigned)x >= 64u) continue;
      s += sq[(bb*HD + y)*WD + x];
    }
  }
  norm[i] = (float)sqrt(s);
  float ms = 0.f;
  const float* mb = mask + (size_t)bb*512*512;
  for (int dh = -1; dh <= 1; ++dh) {
    int y = ph + dh; if ((unsigned)y >= 64u) continue;
    for (int dw = -1; dw <= 1; ++dw) {
      int x = pw + dw; if ((unsigned)x >= 64u) continue;
      ms += mb[(y*8)*512 + x*8];
    }
  }
  float m = (ms == 0.f) ? 1.f : 0.f;
  mmv[i] = m;
  if (m == 0.f) atomicAdd(&zb[bb], 1);
}

// ---------- transpose b to pixel-major b_t[bb][pix][c] (for gather) ----------
__global__ __launch_bounds__(256) void k_btrans(const float* __restrict__ b,
                                                float* __restrict__ bt) {
  __shared__ float tile[32][33];
  int bb = blockIdx.z;
  int c0 = blockIdx.y * 32;
  int p0 = blockIdx.x * 32;
  int tx = threadIdx.x & 31, ty = threadIdx.x >> 5;
  const float* bp = b + (size_t)bb*NC*NPIX;
  #pragma unroll
  for (int r = 0; r < 32; r += 8)
    tile[r + ty][tx] = bp[(size_t)(c0 + r + ty)*NPIX + p0 + tx];
  __syncthreads();
  float* btp = bt + (size_t)bb*NPIX*NC;
  #pragma unroll
  for (int r = 0; r < 32; r += 8)
    btp[(size_t)(p0 + r + ty)*NC + c0 + tx] = tile[tx][r + ty];
}

// ---------- transpose fd,bd to pixel-major: bf16 (GEMM) + fp32 (rescore) ----------
__global__ __launch_bounds__(256) void k_fbtrans(const float* __restrict__ fd,
    const float* __restrict__ bd, unsigned short* __restrict__ fdt,
    unsigned short* __restrict__ bdt, float* __restrict__ fdp,
    float* __restrict__ bdp) {
  __shared__ float tf[32][33], tb[32][33];
  int bb = blockIdx.z;
  int c0 = blockIdx.y * 32;
  int p0 = blockIdx.x * 32;
  int tx = threadIdx.x & 31, ty = threadIdx.x >> 5;
  const float* fp = fd + (size_t)bb*NC*NL;
  const float* bp = bd + (size_t)bb*NC*NL;
  #pragma unroll
  for (int r = 0; r < 32; r += 8) {
    tf[r + ty][tx] = fp[(size_t)(c0 + r + ty)*NL + p0 + tx];
    tb[r + ty][tx] = bp[(size_t)(c0 + r + ty)*NL + p0 + tx];
  }
  __syncthreads();
  #pragma unroll
  for (int r = 0; r < 32; r += 8) {
    float fv = tf[tx][r + ty];
    float bv = tb[tx][r + ty];
    size_t idx = ((size_t)bb*NL + p0 + r + ty)*NC + c0 + tx;
    fdt[idx] = f2bf(fv);
    bdt[idx] = f2bf(bv);
    fdp[idx] = fv;
    bdp[idx] = bv;
  }
}

// ---------- pixel-dot GEMM: D[p][l] = bf16(<fd_pix(p), bd_pix(l)>), K=128 ----------
__global__ __launch_bounds__(256) void k_gemmD(
    const unsigned short* __restrict__ A, const unsigned short* __restrict__ B,
    unsigned short* __restrict__ D) {
  __shared__ __align__(16) unsigned short As[128*32];
  __shared__ __align__(16) unsigned short Bs[128*32];
  int t = threadIdx.x;
  int w = t >> 6, l = t & 63;
  int by = blockIdx.y, bx = blockIdx.x;
  int wr = w >> 1, wc = w & 1;
  f32x4 acc[4][4] = {};
  int aoff[4], boff[4];
  #pragma unroll
  for (int m = 0; m < 4; ++m) {
    aoff[m] = ((wr*64 + m*16 + (l & 15)) * 32 + ((l >> 4) * 8)) * 2;
    boff[m] = ((wc*64 + m*16 + (l & 15)) * 32 + ((l >> 4) * 8)) * 2;
  }
  const char* Ab = (const char*)A;
  const char* Bb = (const char*)B;
  char* AsB = (char*)As;
  char* BsB = (char*)Bs;
  int off = (w*2) * 1024 + l * 16;
  int r0 = off >> 6, cb0 = off & 63;
  int off1 = off + 1024;
  int r1 = off1 >> 6, cb1 = off1 & 63;
  for (int k0 = 0; k0 < 128; k0 += 32) {
    gload_lds16(Ab + ((size_t)(by*128 + r0) * 128 + k0) * 2 + cb0, AsB + (w*2+0)*1024);
    gload_lds16(Ab + ((size_t)(by*128 + r1) * 128 + k0) * 2 + cb1, AsB + (w*2+1)*1024);
    gload_lds16(Bb + ((size_t)(bx*128 + r0) * 128 + k0) * 2 + cb0, BsB + (w*2+0)*1024);
    gload_lds16(Bb + ((size_t)(bx*128 + r1) * 128 + k0) * 2 + cb1, BsB + (w*2+1)*1024);
    __syncthreads();
    s16x8 af[4], bf[4];
    #pragma unroll
    for (int m = 0; m < 4; ++m) af[m] = *(const s16x8*)(AsB + aoff[m]);
    #pragma unroll
    for (int n = 0; n < 4; ++n) bf[n] = *(const s16x8*)(BsB + boff[n]);
    #pragma unroll
    for (int m = 0; m < 4; ++m)
      #pragma unroll
      for (int n = 0; n < 4; ++n)
        acc[m][n] = __builtin_amdgcn_mfma_f32_16x16x32_bf16(af[m], bf[n], acc[m][n], 0, 0, 0);
    __syncthreads();
  }
  int cr = l >> 4;
  int cc = l & 15;
  #pragma unroll
  for (int n = 0; n < 4; ++n) {
    int col = bx*128 + wc*64 + n*16 + cc;
    #pragma unroll
    for (int m = 0; m < 4; ++m) {
      int grow = by*128 + wr*64 + m*16 + cr*4;
      #pragma unroll
      for (int j = 0; j < 4; ++j)
        D[(size_t)(grow + j) * NL + col] = f2bf(acc[m][n][j]);
    }
  }
}

// ---------- horizontal pass: E[p][l] = sum_dw D[p+dw][l+dw], register-shifted ----------
__global__ __launch_bounds__(256) void k_hpass(const unsigned short* __restrict__ D,
                                               unsigned short* __restrict__ E) {
  int p = blockIdx.x;
  int px = p & 63;
  int t = threadIdx.x;
  bool okm = px > 0, okp = px < 63;
  const unsigned short* r0 = D + (size_t)p*NL;
  const unsigned short* rm = D + (size_t)(okm ? p-1 : p)*NL;
  const unsigned short* rp = D + (size_t)(okp ? p+1 : p)*NL;
  #pragma unroll
  for (int ch = 0; ch < 2; ++ch) {
    int l0 = (ch*256 + t) * 8;
    uint4 b0 = *(const uint4*)(r0 + l0);
    int lam = l0 ? (l0 - 8) : 0;
    uint4 am = *(const uint4*)(rm + lam);
    uint4 bm = *(const uint4*)(rm + l0);
    uint4 bp = *(const uint4*)(rp + l0);
    int lcp = (l0 < NL - 8) ? (l0 + 8) : l0;
    uint4 cp = *(const uint4*)(rp + lcp);
    unsigned bmu[4] = {bm.x, bm.y, bm.z, bm.w};
    unsigned bpu[4] = {bp.x, bp.y, bp.z, bp.w};
    unsigned b0u[4] = {b0.x, b0.y, b0.z, b0.w};
    unsigned sm[4], sp[4];
    sm[0] = (am.w >> 16) | (bmu[0] << 16);
    sm[1] = (bmu[0] >> 16) | (bmu[1] << 16);
    sm[2] = (bmu[1] >> 16) | (bmu[2] << 16);
    sm[3] = (bmu[2] >> 16) | (bmu[3] << 16);
    sp[0] = (bpu[0] >> 16) | (bpu[1] << 16);
    sp[1] = (bpu[1] >> 16) | (bpu[2] << 16);
    sp[2] = (bpu[2] >> 16) | (bpu[3] << 16);
    sp[3] = (bpu[3] >> 16) | (cp.x << 16);
    unsigned eo[4];
    #pragma unroll
    for (int k = 0; k < 4; ++k) {
      int j0 = 2*k;
      int lx0 = (l0 + j0) & 63;
      float v0 = (okm && lx0 > 0) ? bf2f((unsigned short)(sm[k] & 0xffffu)) : 0.f;
      v0 += bf2f((unsigned short)(b0u[k] & 0xffffu));
      v0 += (okp && lx0 < 63) ? bf2f((unsigned short)(sp[k] & 0xffffu)) : 0.f;
      int lx1 = (l0 + j0 + 1) & 63;
      float v1 = (okm && lx1 > 0) ? bf2f((unsigned short)(sm[k] >> 16)) : 0.f;
      v1 += bf2f((unsigned short)(b0u[k] >> 16));
      v1 += (okp && lx1 < 63) ? bf2f((unsigned short)(sp[k] >> 16)) : 0.f;
      eo[k] = (unsigned)f2bf(v0) | ((unsigned)f2bf(v1) << 16);
    }
    uint4 outv; outv.x = eo[0]; outv.y = eo[1]; outv.z = eo[2]; outv.w = eo[3];
    *(uint4*)(E + (size_t)p*NL + l0) = outv;
  }
}

// ---------- wave-per-row: vertical stencil + rowmax + scan + exact rescore ----------
// 4 waves/block, wave w owns row p = blockIdx.x*4 + w. No __syncthreads.
__global__ __launch_bounds__(256) void k_rescore4(const unsigned short* __restrict__ E,
    const float* __restrict__ mmv, const float* __restrict__ fdp,
    const float* __restrict__ bdp, const float* __restrict__ nrm,
    const int* __restrict__ zb, int* __restrict__ cnt, Ent* __restrict__ ent,
    float* __restrict__ ooff, int bb) {
  __shared__ float fpat_s[4][1152];   // [r][c] per wave
  __shared__ int   cl_s[4][MAXC];
  __shared__ float cs_s[4][MAXC];
  __shared__ int   cnt_s[4];
  int t = threadIdx.x;
  int w = t >> 6, lane = t & 63;
  int p = blockIdx.x * 4 + w;
  int py = p >> 6;
  int ihp = py, iwp = p & 63;
  float* fpat = fpat_s[w];
  int* cl = cl_s[w];
  float* cs = cs_s[w];
  const float* fdpb = fdp + (size_t)bb*NL*NC;
  const float* bdpb = bdp + (size_t)bb*NL*NC;
  const float* mb = mmv + bb*NL;
  const float* nb = nrm + bb*NL;
  if (lane == 0) cnt_s[w] = 0;

  // stage fpat (coalesced 256 B per iteration), layout [r*128+c]
  #pragma unroll
  for (int it = 0; it < 18; ++it) {
    int idx = it*64 + lane;
    int r = idx >> 7, c = idx & 127;
    int y = ihp + r/3 - 1, x = iwp + (r % 3) - 1;
    fpat[idx] = (((unsigned)y < 64u) && ((unsigned)x < 64u))
                ? fdpb[(size_t)(y*WD + x)*NC + c] : 0.f;
  }

  // pass 1: masked row max
  float mx = -3e38f;
  for (int j = 0; j < 8; ++j) {
    int cb = j*512 + lane*8;
    int ly = cb >> 6;
    bool okm = (py > 0) && (ly > 0);
    bool okp = (py < 63) && (ly < 63);
    size_t a0 = (size_t)p*NL + cb;
    uint4 e0 = *(const uint4*)(E + a0);
    uint4 em = *(const uint4*)(E + (okm ? ((size_t)(p-64)*NL + cb - 64) : a0));
    uint4 ep = *(const uint4*)(E + (okp ? ((size_t)(p+64)*NL + cb + 64) : a0));
    float4 m0 = *(const float4*)(mb + cb);
    float4 m1 = *(const float4*)(mb + cb + 4);
    float4 n0 = *(const float4*)(nb + cb);
    float4 n1 = *(const float4*)(nb + cb + 4);
    unsigned e0u[4] = {e0.x,e0.y,e0.z,e0.w};
    unsigned emu[4] = {em.x,em.y,em.z,em.w};
    unsigned epu[4] = {ep.x,ep.y,ep.z,ep.w};
    float mm8[8] = {m0.x,m0.y,m0.z,m0.w,m1.x,m1.y,m1.z,m1.w};
    float nn8[8] = {n0.x,n0.y,n0.z,n0.w,n1.x,n1.y,n1.z,n1.w};
    #pragma unroll
    for (int k = 0; k < 4; ++k) {
      float v0 = okm ? bf2f((unsigned short)(emu[k] & 0xffffu)) : 0.f;
      v0 += bf2f((unsigned short)(e0u[k] & 0xffffu));
      v0 += okp ? bf2f((unsigned short)(epu[k] & 0xffffu)) : 0.f;
      float v1 = okm ? bf2f((unsigned short)(emu[k] >> 16)) : 0.f;
      v1 += bf2f((unsigned short)(e0u[k] >> 16));
      v1 += okp ? bf2f((unsigned short)(epu[k] >> 16)) : 0.f;
      float s0 = v0 / fmaxf(nn8[2*k], 1e-4f);
      float s1 = v1 / fmaxf(nn8[2*k+1], 1e-4f);
      if (mm8[2*k]   != 0.f) mx = fmaxf(mx, s0);
      if (mm8[2*k+1] != 0.f) mx = fmaxf(mx, s1);
    }
  }
  #pragma unroll
  for (int o = 32; o > 0; o >>= 1) mx = fmaxf(mx, __shfl_xor(mx, o, 64));
  float thr = mx - CUTS;

  // pass 2: collect candidates
  for (int j = 0; j < 8; ++j) {
    int cb = j*512 + lane*8;
    int ly = cb >> 6;
    bool okm = (py > 0) && (ly > 0);
    bool okp = (py < 63) && (ly < 63);
    size_t a0 = (size_t)p*NL + cb;
    uint4 e0 = *(const uint4*)(E + a0);
    uint4 em = *(const uint4*)(E + (okm ? ((size_t)(p-64)*NL + cb - 64) : a0));
    uint4 ep = *(const uint4*)(E + (okp ? ((size_t)(p+64)*NL + cb + 64) : a0));
    float4 m0 = *(const float4*)(mb + cb);
    float4 m1 = *(const float4*)(mb + cb + 4);
    float4 n0 = *(const float4*)(nb + cb);
    float4 n1 = *(const float4*)(nb + cb + 4);
    unsigned e0u[4] = {e0.x,e0.y,e0.z,e0.w};
    unsigned emu[4] = {em.x,em.y,em.z,em.w};
    unsigned epu[4] = {ep.x,ep.y,ep.z,ep.w};
    float mm8[8] = {m0.x,m0.y,m0.z,m0.w,m1.x,m1.y,m1.z,m1.w};
    float nn8[8] = {n0.x,n0.y,n0.z,n0.w,n1.x,n1.y,n1.z,n1.w};
    #pragma unroll
    for (int k = 0; k < 4; ++k) {
      float v0 = okm ? bf2f((unsigned short)(emu[k] & 0xffffu)) : 0.f;
      v0 += bf2f((unsigned short)(e0u[k] & 0xffffu));
      v0 += okp ? bf2f((unsigned short)(epu[k] & 0xffffu)) : 0.f;
      float v1 = okm ? bf2f((unsigned short)(emu[k] >> 16)) : 0.f;
      v1 += bf2f((unsigned short)(e0u[k] >> 16));
      v1 += okp ? bf2f((unsigned short)(epu[k] >> 16)) : 0.f;
      float s0 = v0 / fmaxf(nn8[2*k], 1e-4f);
      float s1 = v1 / fmaxf(nn8[2*k+1], 1e-4f);
      if (mm8[2*k] != 0.f && s0 >= thr) {
        int slot = atomicAdd(&cnt_s[w], 1);
        if (slot < MAXC) cl[slot] = cb + 2*k;
      }
      if (mm8[2*k+1] != 0.f && s1 >= thr) {
        int slot = atomicAdd(&cnt_s[w], 1);
        if (slot < MAXC) cl[slot] = cb + 2*k + 1;
      }
    }
  }
  int nc = cnt_s[w];           // wave-synchronous: atomics complete within wave
  nc = __shfl(nc, 0, 64);      // uniform
  nc = nc < MAXC ? nc : MAXC;
  if (lane == 0 && nc > 1) {   // deterministic order: sort candidates by l
    for (int a = 1; a < nc; ++a) {
      int v = cl[a]; int q = a - 1;
      while (q >= 0 && cl[q] > v) { cl[q+1] = cl[q]; --q; }
      cl[q+1] = v;
    }
  }
  // exact fp32 dot per candidate: lane = channel pair (coalesced)
  for (int a = 0; a < nc; ++a) {
    int lidx = cl[a];          // lane0's sorted view: broadcast via LDS read (all lanes)
    lidx = __shfl(__shfl(lidx, 0, 64), 0, 64); // ensure no divergence artifact
    lidx = cl[a];
    int ph = lidx >> 6, pw = lidx & 63;
    float sum = 0.f;
    #pragma unroll
    for (int r = 0; r < 9; ++r) {
      int y = ph + r/3 - 1, x = pw + (r % 3) - 1;
      bool ok = ((unsigned)y < 64u) && ((unsigned)x < 64u);
      const float* brow = bdpb + (size_t)(y*WD + x)*NC;
      float b0 = ok ? brow[lane] : 0.f;
      float b1 = ok ? brow[lane + 64] : 0.f;
      sum = fmaf(fpat[r*128 + lane], b0, sum);
      sum = fmaf(fpat[r*128 + lane + 64], b1, sum);
    }
    #pragma unroll
    for (int o = 32; o > 0; o >>= 1) sum += __shfl_xor(sum, o, 64);
    if (lane == 0) cs[a] = sum / fmaxf(nb[lidx], 1e-4f);
  }
  if (lane == 0) {
    float smax = -3e38f; int sidx = 0x7fffffff;
    for (int a = 0; a < nc; ++a)
      if (cs[a] > smax) { smax = cs[a]; sidx = cl[a]; }   // sorted by l
    int Z = zb[bb];
    size_t base = (size_t)(bb*NL + p) * MAXENT;
    if (nc == 0) {
      cnt[bb*NL + p] = 0;
      ooff[((bb*2 + 0)*HD + ihp)*WD + iwp] = (float)(0 - ihp);
      ooff[((bb*2 + 1)*HD + ihp)*WD + iwp] = (float)(0 - iwp);
    } else {
      float xm = smax * SM_SCALE;
      if (Z > 0) xm = fmaxf(xm, 0.f);
      float den = 0.f;
      for (int a = 0; a < nc; ++a) {
        float d = cs[a] * SM_SCALE - xm;
        if (d > -CUT) den += expf(d);
      }
      if (Z > 0 && -xm > -CUT) den += (float)Z * expf(-xm);
      int n = 0;
      for (int a = 0; a < nc && n < MAXENT; ++a) {
        float d = cs[a] * SM_SCALE - xm;
        if (d > -CUT) { ent[base + n].l = cl[a]; ent[base + n].p = expf(d) / den; ++n; }
      }
      cnt[bb*NL + p] = n;
      ooff[((bb*2 + 0)*HD + ihp)*WD + iwp] = (float)((sidx >> 6) - ihp);
      ooff[((bb*2 + 1)*HD + ihp)*WD + iwp] = (float)((sidx & 63) - iwp);
    }
  }
}

// ---------- plan: per output pixel, channel-independent contribution list ----------
__global__ void k_plan(const int* __restrict__ cnt, const Ent* __restrict__ ent,
                       int* __restrict__ npl, int* __restrict__ offs,
                       float* __restrict__ wts) {
  int i = blockIdx.x * blockDim.x + threadIdx.x;
  if (i >= NB*NPIX) return;
  int pix = i & (NPIX-1); int bb = i >> 14;
  int oh = pix >> 7, ow = pix & 127;
  int ihlo = (oh - 1) >> 1;
  int iwlo = (ow - 1) >> 1;
  int n = 0;
  #pragma unroll
  for (int a = 0; a < 2; ++a) {
    int ih = ihlo + a;
    if ((unsigned)ih >= 64u) continue;
    #pragma unroll
    for (int d = 0; d < 2; ++d) {
      int iw = iwlo + d;
      if ((unsigned)iw >= 64u) continue;
      int pidx = bb*NL + ih*WD + iw;
      int nn = cnt[pidx];
      const Ent* ep = ent + (size_t)pidx*MAXENT;
      for (int j = 0; j < nn; ++j) {
        Ent e = ep[j];
        int ph = e.l >> 6, pw = e.l & 63;
        int yy = oh + 2*(ph - ih);
        int xx = ow + 2*(pw - iw);
        if ((unsigned)yy < 128u && (unsigned)xx < 128u) {
          offs[((size_t)bb*PLMAX + n)*NPIX + pix] = yy*NW + xx;
          wts[((size_t)bb*PLMAX + n)*NPIX + pix] = e.p;
          ++n;
        }
      }
    }
  }
  npl[i] = n;
}

// ---------- gather v4: thread = (pixel, channel-quad), pixel-major bt ----------
__global__ __launch_bounds__(256) void k_gather4(const float* __restrict__ bt,
    const int* __restrict__ npl, const int* __restrict__ offs,
    const float* __restrict__ wts, float* __restrict__ yout) {
  __shared__ float sm[8][132];
  int bb = blockIdx.y;
  int pixbase = blockIdx.x * 8;
  int t = threadIdx.x;
  int g = t & 31, pl = t >> 5;
  int c0 = g * 4;
  int pix = pixbase + pl;
  const float* btb = bt + (size_t)bb*NPIX*NC;
  int n = npl[bb*NPIX + pix];
  float ax = 0.f, ay = 0.f, az = 0.f, aw = 0.f;
  for (int j = 0; j < n; ++j) {
    int off = offs[((size_t)bb*PLMAX + j)*NPIX + pix];
    float wv = wts[((size_t)bb*PLMAX + j)*NPIX + pix];
    float4 v = *(const float4*)(btb + (size_t)off*NC + c0);
    ax = fmaf(wv, v.x, ax); ay = fmaf(wv, v.y, ay);
    az = fmaf(wv, v.z, az); aw = fmaf(wv, v.w, aw);
  }
  sm[pl][c0+0] = ax; sm[pl][c0+1] = ay; sm[pl][c0+2] = az; sm[pl][c0+3] = aw;
  __syncthreads();
  #pragma unroll
  for (int k = 0; k < 4; ++k) {
    int c = (t >> 3) + 32*k;
    int i = t & 7;
    yout[((size_t)bb*NC + c)*NPIX + pixbase + i] = sm[i][c] * 0.25f;
  }
}

extern "C" void kernel_launch(void* const* d_in, const int* in_sizes, int n_in,
                              void* d_out, int out_size, void* d_ws, size_t ws_size,
                              hipStream_t stream) {
  const float* f = (const float*)d_in[0];
  const float* b = (const float*)d_in[1];
  const float* mask = (const float*)d_in[2];
  float* out = (float*)d_out;

  char* w = (char*)d_ws;
  float* fd   = (float*)w;  w += (size_t)NB*NC*HD*WD*4;
  float* bd   = (float*)w;  w += (size_t)NB*NC*HD*WD*4;
  double* sq  = (double*)w; w += (size_t)NB*HD*WD*8;
  float* norm = (float*)w;  w += (size_t)NB*NL*4;
  float* mmv  = (float*)w;  w += (size_t)NB*NL*4;
  int* cnt    = (int*)w;    w += (size_t)NB*NL*4;
  Ent* ent    = (Ent*)w;    w += (size_t)NB*NL*MAXENT*sizeof(Ent);
  unsigned short* fdt = (unsigned short*)w; w += (size_t)NB*NL*NC*2;
  unsigned short* bdt = (unsigned short*)w; w += (size_t)NB*NL*NC*2;
  float* fdp  = (float*)w;  w += (size_t)NB*NL*NC*4;
  float* bdp  = (float*)w;  w += (size_t)NB*NL*NC*4;
  int* zb     = (int*)w;    w += 64;
  int* npl    = (int*)w;    w += (size_t)NB*NPIX*4;
  int* offs   = (int*)w;    w += (size_t)NB*PLMAX*NPIX*4;
  float* wts  = (float*)w;  w += (size_t)NB*PLMAX*NPIX*4;
  // D (32 MB, in-loop) aliases bt (33.5 MB, post-loop)
  float* bt   = (float*)w;
  unsigned short* D = (unsigned short*)w; w += (size_t)NB*NPIX*NC*4;
  unsigned short* E = (unsigned short*)w;   // 32 MB, reused per batch

  int n1 = NB*NC*HD*WD;
  k_prep<<<(n1+255)/256, 256, 0, stream>>>(f, b, fd, bd);
  k_sq<<<(NB*HD*WD+255)/256, 256, 0, stream>>>(bd, sq);
  hipMemsetAsync(zb, 0, 64, stream);
  k_normmm<<<(NB*NL+255)/256, 256, 0, stream>>>(sq, mask, norm, mmv, zb);
  k_fbtrans<<<dim3(NL/32, NC/32, NB), 256, 0, stream>>>(fd, bd, fdt, bdt, fdp, bdp);

  float* ooff = out + (size_t)NB*NC*NH*NW;
  for (int bb = 0; bb < NB; ++bb) {
    k_gemmD<<<dim3(32, 32), 256, 0, stream>>>(fdt + (size_t)bb*NL*NC,
                                              bdt + (size_t)bb*NL*NC, D);
    k_hpass<<<NL, 256, 0, stream>>>(D, E);
    k_rescore4<<<NL/4, 256, 0, stream>>>(E, mmv, fdp, bdp, norm, zb, cnt, ent, ooff, bb);
  }
  k_btrans<<<dim3(NPIX/32, NC/32, NB), 256, 0, stream>>>(b, bt);
  k_plan<<<(NB*NPIX+255)/256, 256, 0, stream>>>(cnt, ent, npl, offs, wts);
  k_gather4<<<dim3(NPIX/8, NB), 256, 0, stream>>>(bt, npl, offs, wts, out);
}

// Round 11
// 332.140 us; speedup vs baseline: 1.2196x; 1.1582x over previous
//
#include <hip/hip_runtime.h>
#include <cmath>

#define NB 4
#define NC 128
#define NH 128
#define NW 128
#define HD 64
#define WD 64
#define NL 4096      // 64*64 positions / patches
#define NPIX 16384   // 128*128 output pixels per batch
#define SM_SCALE 2550.0f
#define CUT 40.0f
#define CUTS 0.216f  // candidate margin in score units
#define MAXENT 8
#define MAXC 256
#define PLMAX 32     // 4 positions x MAXENT survivors

struct Ent { int l; float p; };

typedef __attribute__((ext_vector_type(4))) float f32x4;
typedef __attribute__((ext_vector_type(8))) short s16x8;

__device__ __forceinline__ unsigned short f2bf(float x) {
  unsigned u = __float_as_uint(x);
  return (unsigned short)((u + 0x7fffu + ((u >> 16) & 1u)) >> 16);
}
__device__ __forceinline__ float bf2f(unsigned short h) {
  return __uint_as_float(((unsigned)h) << 16);
}
__device__ __forceinline__ void gload_lds16(const void* g, void* l) {
  __builtin_amdgcn_global_load_lds(
      (const __attribute__((address_space(1))) void*)g,
      (__attribute__((address_space(3))) void*)l, 16, 0, 0);
}

// ---------- prep ----------
__global__ void k_prep(const float* __restrict__ f, const float* __restrict__ b,
                       float* __restrict__ fd, float* __restrict__ bd) {
  int i = blockIdx.x * blockDim.x + threadIdx.x;
  if (i >= NB*NC*HD*WD) return;
  int x = i & 63, y = (i >> 6) & 63, c = (i >> 12) & 127, bb = i >> 19;
  int src = ((bb*NC + c)*NH + 2*y)*NW + 2*x;
  fd[i] = f[src];
  bd[i] = b[src];
}

__global__ void k_sq(const float* __restrict__ bd, double* __restrict__ sq) {
  int i = blockIdx.x * blockDim.x + threadIdx.x;
  if (i >= NB*HD*WD) return;
  int x = i & 63, y = (i >> 6) & 63, bb = i >> 12;
  double s = 0.0;
  const float* p = bd + (size_t)bb*NC*HD*WD + y*WD + x;
  for (int c = 0; c < NC; ++c) {
    double v = (double)p[(size_t)c*HD*WD];
    s += v*v;
  }
  sq[i] = s;
}

// norm, masked reciprocal (NaN when masked), zero-count
__global__ void k_normmm(const double* __restrict__ sq, const float* __restrict__ mask,
                         float* __restrict__ norm, float* __restrict__ rnm,
                         int* __restrict__ zb) {
  int i = blockIdx.x * blockDim.x + threadIdx.x;
  if (i >= NB*NL) return;
  int pw = i & 63, ph = (i >> 6) & 63, bb = i >> 12;
  double s = 0.0;
  for (int dh = -1; dh <= 1; ++dh) {
    int y = ph + dh; if ((unsigned)y >= 64u) continue;
    for (int dw = -1; dw <= 1; ++dw) {
      int x = pw + dw; if ((unsigned)x >= 64u) continue;
      s += sq[(bb*HD + y)*WD + x];
    }
  }
  float nv = (float)sqrt(s);
  norm[i] = nv;
  float ms = 0.f;
  const float* mb = mask + (size_t)bb*512*512;
  for (int dh = -1; dh <= 1; ++dh) {
    int y = ph + dh; if ((unsigned)y >= 64u) continue;
    for (int dw = -1; dw <= 1; ++dw) {
      int x = pw + dw; if ((unsigned)x >= 64u) continue;
      ms += mb[(y*8)*512 + x*8];
    }
  }
  bool unmasked = (ms == 0.f);
  rnm[i] = unmasked ? (1.f / fmaxf(nv, 1e-4f)) : __uint_as_float(0x7fc00000u);
  if (!unmasked) atomicAdd(&zb[bb], 1);
}

// ---------- transpose b to pixel-major b_t[bb][pix][c] (for gather) ----------
__global__ __launch_bounds__(256) void k_btrans(const float* __restrict__ b,
                                                float* __restrict__ bt) {
  __shared__ float tile[32][33];
  int bb = blockIdx.z;
  int c0 = blockIdx.y * 32;
  int p0 = blockIdx.x * 32;
  int tx = threadIdx.x & 31, ty = threadIdx.x >> 5;
  const float* bp = b + (size_t)bb*NC*NPIX;
  #pragma unroll
  for (int r = 0; r < 32; r += 8)
    tile[r + ty][tx] = bp[(size_t)(c0 + r + ty)*NPIX + p0 + tx];
  __syncthreads();
  float* btp = bt + (size_t)bb*NPIX*NC;
  #pragma unroll
  for (int r = 0; r < 32; r += 8)
    btp[(size_t)(p0 + r + ty)*NC + c0 + tx] = tile[tx][r + ty];
}

// ---------- transpose fd,bd to pixel-major: bf16 (GEMM) + fp32 (rescore) ----------
__global__ __launch_bounds__(256) void k_fbtrans(const float* __restrict__ fd,
    const float* __restrict__ bd, unsigned short* __restrict__ fdt,
    unsigned short* __restrict__ bdt, float* __restrict__ fdp,
    float* __restrict__ bdp) {
  __shared__ float tf[32][33], tb[32][33];
  int bb = blockIdx.z;
  int c0 = blockIdx.y * 32;
  int p0 = blockIdx.x * 32;
  int tx = threadIdx.x & 31, ty = threadIdx.x >> 5;
  const float* fp = fd + (size_t)bb*NC*NL;
  const float* bp = bd + (size_t)bb*NC*NL;
  #pragma unroll
  for (int r = 0; r < 32; r += 8) {
    tf[r + ty][tx] = fp[(size_t)(c0 + r + ty)*NL + p0 + tx];
    tb[r + ty][tx] = bp[(size_t)(c0 + r + ty)*NL + p0 + tx];
  }
  __syncthreads();
  #pragma unroll
  for (int r = 0; r < 32; r += 8) {
    float fv = tf[tx][r + ty];
    float bv = tb[tx][r + ty];
    size_t idx = ((size_t)bb*NL + p0 + r + ty)*NC + c0 + tx;
    fdt[idx] = f2bf(fv);
    bdt[idx] = f2bf(bv);
    fdp[idx] = fv;
    bdp[idx] = bv;
  }
}

// ---------- pixel-dot GEMM: D[p][l] = bf16(<fd_pix(p), bd_pix(l)>), K=128 ----------
__global__ __launch_bounds__(256) void k_gemmD(
    const unsigned short* __restrict__ A, const unsigned short* __restrict__ B,
    unsigned short* __restrict__ D) {
  __shared__ __align__(16) unsigned short As[128*32];
  __shared__ __align__(16) unsigned short Bs[128*32];
  int t = threadIdx.x;
  int w = t >> 6, l = t & 63;
  int by = blockIdx.y, bx = blockIdx.x;
  int wr = w >> 1, wc = w & 1;
  f32x4 acc[4][4] = {};
  int aoff[4], boff[4];
  #pragma unroll
  for (int m = 0; m < 4; ++m) {
    aoff[m] = ((wr*64 + m*16 + (l & 15)) * 32 + ((l >> 4) * 8)) * 2;
    boff[m] = ((wc*64 + m*16 + (l & 15)) * 32 + ((l >> 4) * 8)) * 2;
  }
  const char* Ab = (const char*)A;
  const char* Bb = (const char*)B;
  char* AsB = (char*)As;
  char* BsB = (char*)Bs;
  int off = (w*2) * 1024 + l * 16;
  int r0 = off >> 6, cb0 = off & 63;
  int off1 = off + 1024;
  int r1 = off1 >> 6, cb1 = off1 & 63;
  for (int k0 = 0; k0 < 128; k0 += 32) {
    gload_lds16(Ab + ((size_t)(by*128 + r0) * 128 + k0) * 2 + cb0, AsB + (w*2+0)*1024);
    gload_lds16(Ab + ((size_t)(by*128 + r1) * 128 + k0) * 2 + cb1, AsB + (w*2+1)*1024);
    gload_lds16(Bb + ((size_t)(bx*128 + r0) * 128 + k0) * 2 + cb0, BsB + (w*2+0)*1024);
    gload_lds16(Bb + ((size_t)(bx*128 + r1) * 128 + k0) * 2 + cb1, BsB + (w*2+1)*1024);
    __syncthreads();
    s16x8 af[4], bf[4];
    #pragma unroll
    for (int m = 0; m < 4; ++m) af[m] = *(const s16x8*)(AsB + aoff[m]);
    #pragma unroll
    for (int n = 0; n < 4; ++n) bf[n] = *(const s16x8*)(BsB + boff[n]);
    #pragma unroll
    for (int m = 0; m < 4; ++m)
      #pragma unroll
      for (int n = 0; n < 4; ++n)
        acc[m][n] = __builtin_amdgcn_mfma_f32_16x16x32_bf16(af[m], bf[n], acc[m][n], 0, 0, 0);
    __syncthreads();
  }
  int cr = l >> 4;
  int cc = l & 15;
  #pragma unroll
  for (int n = 0; n < 4; ++n) {
    int col = bx*128 + wc*64 + n*16 + cc;
    #pragma unroll
    for (int m = 0; m < 4; ++m) {
      int grow = by*128 + wr*64 + m*16 + cr*4;
      #pragma unroll
      for (int j = 0; j < 4; ++j)
        D[(size_t)(grow + j) * NL + col] = f2bf(acc[m][n][j]);
    }
  }
}

// ---------- horizontal pass: E[p][l] = sum_dw D[p+dw][l+dw], register-shifted ----------
__global__ __launch_bounds__(256) void k_hpass(const unsigned short* __restrict__ D,
                                               unsigned short* __restrict__ E) {
  int p = blockIdx.x;
  int px = p & 63;
  int t = threadIdx.x;
  bool okm = px > 0, okp = px < 63;
  const unsigned short* r0 = D + (size_t)p*NL;
  const unsigned short* rm = D + (size_t)(okm ? p-1 : p)*NL;
  const unsigned short* rp = D + (size_t)(okp ? p+1 : p)*NL;
  #pragma unroll
  for (int ch = 0; ch < 2; ++ch) {
    int l0 = (ch*256 + t) * 8;
    uint4 b0 = *(const uint4*)(r0 + l0);
    int lam = l0 ? (l0 - 8) : 0;
    uint4 am = *(const uint4*)(rm + lam);
    uint4 bm = *(const uint4*)(rm + l0);
    uint4 bp = *(const uint4*)(rp + l0);
    int lcp = (l0 < NL - 8) ? (l0 + 8) : l0;
    uint4 cp = *(const uint4*)(rp + lcp);
    unsigned bmu[4] = {bm.x, bm.y, bm.z, bm.w};
    unsigned bpu[4] = {bp.x, bp.y, bp.z, bp.w};
    unsigned b0u[4] = {b0.x, b0.y, b0.z, b0.w};
    unsigned sm[4], sp[4];
    sm[0] = (am.w >> 16) | (bmu[0] << 16);
    sm[1] = (bmu[0] >> 16) | (bmu[1] << 16);
    sm[2] = (bmu[1] >> 16) | (bmu[2] << 16);
    sm[3] = (bmu[2] >> 16) | (bmu[3] << 16);
    sp[0] = (bpu[0] >> 16) | (bpu[1] << 16);
    sp[1] = (bpu[1] >> 16) | (bpu[2] << 16);
    sp[2] = (bpu[2] >> 16) | (bpu[3] << 16);
    sp[3] = (bpu[3] >> 16) | (cp.x << 16);
    unsigned eo[4];
    #pragma unroll
    for (int k = 0; k < 4; ++k) {
      int j0 = 2*k;
      int lx0 = (l0 + j0) & 63;
      float v0 = (okm && lx0 > 0) ? bf2f((unsigned short)(sm[k] & 0xffffu)) : 0.f;
      v0 += bf2f((unsigned short)(b0u[k] & 0xffffu));
      v0 += (okp && lx0 < 63) ? bf2f((unsigned short)(sp[k] & 0xffffu)) : 0.f;
      int lx1 = (l0 + j0 + 1) & 63;
      float v1 = (okm && lx1 > 0) ? bf2f((unsigned short)(sm[k] >> 16)) : 0.f;
      v1 += bf2f((unsigned short)(b0u[k] >> 16));
      v1 += (okp && lx1 < 63) ? bf2f((unsigned short)(sp[k] >> 16)) : 0.f;
      eo[k] = (unsigned)f2bf(v0) | ((unsigned)f2bf(v1) << 16);
    }
    uint4 outv; outv.x = eo[0]; outv.y = eo[1]; outv.z = eo[2]; outv.w = eo[3];
    *(uint4*)(E + (size_t)p*NL + l0) = outv;
  }
}

// ---------- wave-per-row: vertical stencil + rowmax + scan + exact rescore ----------
// 4 waves/block, wave w owns row p = blockIdx.x*4 + w. No __syncthreads.
// Masking via NaN in rnm: fmaxf ignores NaN; NaN >= thr is false.
__global__ __launch_bounds__(256) void k_rescore4(const unsigned short* __restrict__ E,
    const float* __restrict__ rnm, const float* __restrict__ fdp,
    const float* __restrict__ bdp, const float* __restrict__ nrm,
    const int* __restrict__ zb, int* __restrict__ cnt, Ent* __restrict__ ent,
    float* __restrict__ ooff, int bb) {
  __shared__ float fpat_s[4][1152];   // [r][c] per wave
  __shared__ int   cl_s[4][MAXC];
  __shared__ float cs_s[4][MAXC];
  __shared__ int   cnt_s[4];
  int t = threadIdx.x;
  int w = t >> 6, lane = t & 63;
  int p = blockIdx.x * 4 + w;
  int py = p >> 6;
  int ihp = py, iwp = p & 63;
  float* fpat = fpat_s[w];
  int* cl = cl_s[w];
  float* cs = cs_s[w];
  const float* fdpb = fdp + (size_t)bb*NL*NC;
  const float* bdpb = bdp + (size_t)bb*NL*NC;
  const float* rb = rnm + bb*NL;
  const float* nb = nrm + bb*NL;
  if (lane == 0) cnt_s[w] = 0;

  // stage fpat (coalesced 256 B per iteration), layout [r*128+c]
  #pragma unroll
  for (int it = 0; it < 18; ++it) {
    int idx = it*64 + lane;
    int r = idx >> 7, c = idx & 127;
    int y = ihp + r/3 - 1, x = iwp + (r % 3) - 1;
    fpat[idx] = (((unsigned)y < 64u) && ((unsigned)x < 64u))
                ? fdpb[(size_t)(y*WD + x)*NC + c] : 0.f;
  }

  // pass 1: masked row max (mask folded into rnm as NaN)
  float mx = -3e38f;
  for (int j = 0; j < 8; ++j) {
    int cb = j*512 + lane*8;
    int ly = cb >> 6;
    bool okm = (py > 0) && (ly > 0);
    bool okp = (py < 63) && (ly < 63);
    size_t a0 = (size_t)p*NL + cb;
    uint4 e0 = *(const uint4*)(E + a0);
    uint4 em = *(const uint4*)(E + (okm ? ((size_t)(p-64)*NL + cb - 64) : a0));
    uint4 ep = *(const uint4*)(E + (okp ? ((size_t)(p+64)*NL + cb + 64) : a0));
    float4 r0 = *(const float4*)(rb + cb);
    float4 r1 = *(const float4*)(rb + cb + 4);
    unsigned e0u[4] = {e0.x,e0.y,e0.z,e0.w};
    unsigned emu[4] = {em.x,em.y,em.z,em.w};
    unsigned epu[4] = {ep.x,ep.y,ep.z,ep.w};
    float rr8[8] = {r0.x,r0.y,r0.z,r0.w,r1.x,r1.y,r1.z,r1.w};
    #pragma unroll
    for (int k = 0; k < 4; ++k) {
      float v0 = okm ? bf2f((unsigned short)(emu[k] & 0xffffu)) : 0.f;
      v0 += bf2f((unsigned short)(e0u[k] & 0xffffu));
      v0 += okp ? bf2f((unsigned short)(epu[k] & 0xffffu)) : 0.f;
      float v1 = okm ? bf2f((unsigned short)(emu[k] >> 16)) : 0.f;
      v1 += bf2f((unsigned short)(e0u[k] >> 16));
      v1 += okp ? bf2f((unsigned short)(epu[k] >> 16)) : 0.f;
      mx = fmaxf(mx, v0 * rr8[2*k]);     // NaN ignored by fmaxf
      mx = fmaxf(mx, v1 * rr8[2*k+1]);
    }
  }
  #pragma unroll
  for (int o = 32; o > 0; o >>= 1) mx = fmaxf(mx, __shfl_xor(mx, o, 64));
  float thr = mx - CUTS;

  // pass 2: collect candidates (NaN >= thr is false)
  for (int j = 0; j < 8; ++j) {
    int cb = j*512 + lane*8;
    int ly = cb >> 6;
    bool okm = (py > 0) && (ly > 0);
    bool okp = (py < 63) && (ly < 63);
    size_t a0 = (size_t)p*NL + cb;
    uint4 e0 = *(const uint4*)(E + a0);
    uint4 em = *(const uint4*)(E + (okm ? ((size_t)(p-64)*NL + cb - 64) : a0));
    uint4 ep = *(const uint4*)(E + (okp ? ((size_t)(p+64)*NL + cb + 64) : a0));
    float4 r0 = *(const float4*)(rb + cb);
    float4 r1 = *(const float4*)(rb + cb + 4);
    unsigned e0u[4] = {e0.x,e0.y,e0.z,e0.w};
    unsigned emu[4] = {em.x,em.y,em.z,em.w};
    unsigned epu[4] = {ep.x,ep.y,ep.z,ep.w};
    float rr8[8] = {r0.x,r0.y,r0.z,r0.w,r1.x,r1.y,r1.z,r1.w};
    #pragma unroll
    for (int k = 0; k < 4; ++k) {
      float v0 = okm ? bf2f((unsigned short)(emu[k] & 0xffffu)) : 0.f;
      v0 += bf2f((unsigned short)(e0u[k] & 0xffffu));
      v0 += okp ? bf2f((unsigned short)(epu[k] & 0xffffu)) : 0.f;
      float v1 = okm ? bf2f((unsigned short)(emu[k] >> 16)) : 0.f;
      v1 += bf2f((unsigned short)(e0u[k] >> 16));
      v1 += okp ? bf2f((unsigned short)(epu[k] >> 16)) : 0.f;
      float s0 = v0 * rr8[2*k];
      float s1 = v1 * rr8[2*k+1];
      if (s0 >= thr) {
        int slot = atomicAdd(&cnt_s[w], 1);
        if (slot < MAXC) cl[slot] = cb + 2*k;
      }
      if (s1 >= thr) {
        int slot = atomicAdd(&cnt_s[w], 1);
        if (slot < MAXC) cl[slot] = cb + 2*k + 1;
      }
    }
  }
  int nc = cnt_s[w];           // wave-synchronous: atomics complete within wave
  nc = __shfl(nc, 0, 64);
  nc = nc < MAXC ? nc : MAXC;
  if (lane == 0 && nc > 1) {   // deterministic order: sort candidates by l
    for (int a = 1; a < nc; ++a) {
      int v = cl[a]; int q = a - 1;
      while (q >= 0 && cl[q] > v) { cl[q+1] = cl[q]; --q; }
      cl[q+1] = v;
    }
  }
  // exact fp32 dot per candidate: lane = channel pair (coalesced)
  for (int a = 0; a < nc; ++a) {
    int lidx = cl[a];
    int ph = lidx >> 6, pw = lidx & 63;
    float sum = 0.f;
    #pragma unroll
    for (int r = 0; r < 9; ++r) {
      int y = ph + r/3 - 1, x = pw + (r % 3) - 1;
      bool ok = ((unsigned)y < 64u) && ((unsigned)x < 64u);
      const float* brow = bdpb + (size_t)(y*WD + x)*NC;
      float b0 = ok ? brow[lane] : 0.f;
      float b1 = ok ? brow[lane + 64] : 0.f;
      sum = fmaf(fpat[r*128 + lane], b0, sum);
      sum = fmaf(fpat[r*128 + lane + 64], b1, sum);
    }
    #pragma unroll
    for (int o = 32; o > 0; o >>= 1) sum += __shfl_xor(sum, o, 64);
    if (lane == 0) cs[a] = sum / fmaxf(nb[lidx], 1e-4f);
  }
  if (lane == 0) {
    float smax = -3e38f; int sidx = 0x7fffffff;
    for (int a = 0; a < nc; ++a)
      if (cs[a] > smax) { smax = cs[a]; sidx = cl[a]; }   // sorted by l
    int Z = zb[bb];
    size_t base = (size_t)(bb*NL + p) * MAXENT;
    if (nc == 0) {
      cnt[bb*NL + p] = 0;
      ooff[((bb*2 + 0)*HD + ihp)*WD + iwp] = (float)(0 - ihp);
      ooff[((bb*2 + 1)*HD + ihp)*WD + iwp] = (float)(0 - iwp);
    } else {
      float xm = smax * SM_SCALE;
      if (Z > 0) xm = fmaxf(xm, 0.f);
      float den = 0.f;
      for (int a = 0; a < nc; ++a) {
        float d = cs[a] * SM_SCALE - xm;
        if (d > -CUT) den += expf(d);
      }
      if (Z > 0 && -xm > -CUT) den += (float)Z * expf(-xm);
      int n = 0;
      for (int a = 0; a < nc && n < MAXENT; ++a) {
        float d = cs[a] * SM_SCALE - xm;
        if (d > -CUT) { ent[base + n].l = cl[a]; ent[base + n].p = expf(d) / den; ++n; }
      }
      cnt[bb*NL + p] = n;
      ooff[((bb*2 + 0)*HD + ihp)*WD + iwp] = (float)((sidx >> 6) - ihp);
      ooff[((bb*2 + 1)*HD + ihp)*WD + iwp] = (float)((sidx & 63) - iwp);
    }
  }
}

// ---------- plan: per output pixel, channel-independent contribution list ----------
__global__ void k_plan(const int* __restrict__ cnt, const Ent* __restrict__ ent,
                       int* __restrict__ npl, int* __restrict__ offs,
                       float* __restrict__ wts) {
  int i = blockIdx.x * blockDim.x + threadIdx.x;
  if (i >= NB*NPIX) return;
  int pix = i & (NPIX-1); int bb = i >> 14;
  int oh = pix >> 7, ow = pix & 127;
  int ihlo = (oh - 1) >> 1;
  int iwlo = (ow - 1) >> 1;
  int n = 0;
  #pragma unroll
  for (int a = 0; a < 2; ++a) {
    int ih = ihlo + a;
    if ((unsigned)ih >= 64u) continue;
    #pragma unroll
    for (int d = 0; d < 2; ++d) {
      int iw = iwlo + d;
      if ((unsigned)iw >= 64u) continue;
      int pidx = bb*NL + ih*WD + iw;
      int nn = cnt[pidx];
      const Ent* ep = ent + (size_t)pidx*MAXENT;
      for (int j = 0; j < nn; ++j) {
        Ent e = ep[j];
        int ph = e.l >> 6, pw = e.l & 63;
        int yy = oh + 2*(ph - ih);
        int xx = ow + 2*(pw - iw);
        if ((unsigned)yy < 128u && (unsigned)xx < 128u) {
          offs[((size_t)bb*PLMAX + n)*NPIX + pix] = yy*NW + xx;
          wts[((size_t)bb*PLMAX + n)*NPIX + pix] = e.p;
          ++n;
        }
      }
    }
  }
  npl[i] = n;
}

// ---------- gather v4: thread = (pixel, channel-quad), pixel-major bt ----------
__global__ __launch_bounds__(256) void k_gather4(const float* __restrict__ bt,
    const int* __restrict__ npl, const int* __restrict__ offs,
    const float* __restrict__ wts, float* __restrict__ yout) {
  __shared__ float sm[8][132];
  int bb = blockIdx.y;
  int pixbase = blockIdx.x * 8;
  int t = threadIdx.x;
  int g = t & 31, pl = t >> 5;
  int c0 = g * 4;
  int pix = pixbase + pl;
  const float* btb = bt + (size_t)bb*NPIX*NC;
  int n = npl[bb*NPIX + pix];
  float ax = 0.f, ay = 0.f, az = 0.f, aw = 0.f;
  for (int j = 0; j < n; ++j) {
    int off = offs[((size_t)bb*PLMAX + j)*NPIX + pix];
    float wv = wts[((size_t)bb*PLMAX + j)*NPIX + pix];
    float4 v = *(const float4*)(btb + (size_t)off*NC + c0);
    ax = fmaf(wv, v.x, ax); ay = fmaf(wv, v.y, ay);
    az = fmaf(wv, v.z, az); aw = fmaf(wv, v.w, aw);
  }
  sm[pl][c0+0] = ax; sm[pl][c0+1] = ay; sm[pl][c0+2] = az; sm[pl][c0+3] = aw;
  __syncthreads();
  #pragma unroll
  for (int k = 0; k < 4; ++k) {
    int c = (t >> 3) + 32*k;
    int i = t & 7;
    yout[((size_t)bb*NC + c)*NPIX + pixbase + i] = sm[i][c] * 0.25f;
  }
}

extern "C" void kernel_launch(void* const* d_in, const int* in_sizes, int n_in,
                              void* d_out, int out_size, void* d_ws, size_t ws_size,
                              hipStream_t stream) {
  const float* f = (const float*)d_in[0];
  const float* b = (const float*)d_in[1];
  const float* mask = (const float*)d_in[2];
  float* out = (float*)d_out;

  char* w = (char*)d_ws;
  float* fd   = (float*)w;  w += (size_t)NB*NC*HD*WD*4;
  float* bd   = (float*)w;  w += (size_t)NB*NC*HD*WD*4;
  double* sq  = (double*)w; w += (size_t)NB*HD*WD*8;
  float* norm = (float*)w;  w += (size_t)NB*NL*4;
  float* rnm  = (float*)w;  w += (size_t)NB*NL*4;
  int* cnt    = (int*)w;    w += (size_t)NB*NL*4;
  Ent* ent    = (Ent*)w;    w += (size_t)NB*NL*MAXENT*sizeof(Ent);
  unsigned short* fdt = (unsigned short*)w; w += (size_t)NB*NL*NC*2;
  unsigned short* bdt = (unsigned short*)w; w += (size_t)NB*NL*NC*2;
  float* fdp  = (float*)w;  w += (size_t)NB*NL*NC*4;
  float* bdp  = (float*)w;  w += (size_t)NB*NL*NC*4;
  int* zb     = (int*)w;    w += 64;
  int* npl    = (int*)w;    w += (size_t)NB*NPIX*4;
  int* offs   = (int*)w;    w += (size_t)NB*PLMAX*NPIX*4;
  float* wts  = (float*)w;  w += (size_t)NB*PLMAX*NPIX*4;
  // D (32 MB, in-loop) aliases bt (33.5 MB, post-loop)
  float* bt   = (float*)w;
  unsigned short* D = (unsigned short*)w; w += (size_t)NB*NPIX*NC*4;
  unsigned short* E = (unsigned short*)w;   // 32 MB, reused per batch

  int n1 = NB*NC*HD*WD;
  k_prep<<<(n1+255)/256, 256, 0, stream>>>(f, b, fd, bd);
  k_sq<<<(NB*HD*WD+255)/256, 256, 0, stream>>>(bd, sq);
  hipMemsetAsync(zb, 0, 64, stream);
  k_normmm<<<(NB*NL+255)/256, 256, 0, stream>>>(sq, mask, norm, rnm, zb);
  k_fbtrans<<<dim3(NL/32, NC/32, NB), 256, 0, stream>>>(fd, bd, fdt, bdt, fdp, bdp);

  float* ooff = out + (size_t)NB*NC*NH*NW;
  for (int bb = 0; bb < NB; ++bb) {
    k_gemmD<<<dim3(32, 32), 256, 0, stream>>>(fdt + (size_t)bb*NL*NC,
                                              bdt + (size_t)bb*NL*NC, D);
    k_hpass<<<NL, 256, 0, stream>>>(D, E);
    k_rescore4<<<NL/4, 256, 0, stream>>>(E, rnm, fdp, bdp, norm, zb, cnt, ent, ooff, bb);
  }
  k_btrans<<<dim3(NPIX/32, NC/32, NB), 256, 0, stream>>>(b, bt);
  k_plan<<<(NB*NPIX+255)/256, 256, 0, stream>>>(cnt, ent, npl, offs, wts);
  k_gather4<<<dim3(NPIX/8, NB), 256, 0, stream>>>(bt, npl, offs, wts, out);
}

// Round 12
// 321.560 us; speedup vs baseline: 1.2597x; 1.0329x over previous
//
#include <hip/hip_runtime.h>
#include <cmath>

#define NB 4
#define NC 128
#define NH 128
#define NW 128
#define HD 64
#define WD 64
#define NL 4096      // 64*64 positions / patches
#define NPIX 16384   // 128*128 output pixels per batch
#define SM_SCALE 2550.0f
#define CUT 40.0f
#define CUTS 0.216f  // candidate margin in score units
#define MAXENT 8
#define MAXC 256
#define PLMAX 32     // 4 positions x MAXENT survivors

struct Ent { int l; float p; };

typedef __attribute__((ext_vector_type(4))) float f32x4;
typedef __attribute__((ext_vector_type(8))) short s16x8;

__device__ __forceinline__ unsigned short f2bf(float x) {
  unsigned u = __float_as_uint(x);
  return (unsigned short)((u + 0x7fffu + ((u >> 16) & 1u)) >> 16);
}
__device__ __forceinline__ float bf2f(unsigned short h) {
  return __uint_as_float(((unsigned)h) << 16);
}
__device__ __forceinline__ void gload_lds16(const void* g, void* l) {
  __builtin_amdgcn_global_load_lds(
      (const __attribute__((address_space(1))) void*)g,
      (__attribute__((address_space(3))) void*)l, 16, 0, 0);
}

// ---------- prep ----------
__global__ void k_prep(const float* __restrict__ f, const float* __restrict__ b,
                       float* __restrict__ fd, float* __restrict__ bd) {
  int i = blockIdx.x * blockDim.x + threadIdx.x;
  if (i >= NB*NC*HD*WD) return;
  int x = i & 63, y = (i >> 6) & 63, c = (i >> 12) & 127, bb = i >> 19;
  int src = ((bb*NC + c)*NH + 2*y)*NW + 2*x;
  fd[i] = f[src];
  bd[i] = b[src];
}

__global__ void k_sq(const float* __restrict__ bd, double* __restrict__ sq) {
  int i = blockIdx.x * blockDim.x + threadIdx.x;
  if (i >= NB*HD*WD) return;
  int x = i & 63, y = (i >> 6) & 63, bb = i >> 12;
  double s = 0.0;
  const float* p = bd + (size_t)bb*NC*HD*WD + y*WD + x;
  for (int c = 0; c < NC; ++c) {
    double v = (double)p[(size_t)c*HD*WD];
    s += v*v;
  }
  sq[i] = s;
}

// norm, masked reciprocal (NaN when masked), zero-count
__global__ void k_normmm(const double* __restrict__ sq, const float* __restrict__ mask,
                         float* __restrict__ norm, float* __restrict__ rnm,
                         int* __restrict__ zb) {
  int i = blockIdx.x * blockDim.x + threadIdx.x;
  if (i >= NB*NL) return;
  int pw = i & 63, ph = (i >> 6) & 63, bb = i >> 12;
  double s = 0.0;
  for (int dh = -1; dh <= 1; ++dh) {
    int y = ph + dh; if ((unsigned)y >= 64u) continue;
    for (int dw = -1; dw <= 1; ++dw) {
      int x = pw + dw; if ((unsigned)x >= 64u) continue;
      s += sq[(bb*HD + y)*WD + x];
    }
  }
  float nv = (float)sqrt(s);
  norm[i] = nv;
  float ms = 0.f;
  const float* mb = mask + (size_t)bb*512*512;
  for (int dh = -1; dh <= 1; ++dh) {
    int y = ph + dh; if ((unsigned)y >= 64u) continue;
    for (int dw = -1; dw <= 1; ++dw) {
      int x = pw + dw; if ((unsigned)x >= 64u) continue;
      ms += mb[(y*8)*512 + x*8];
    }
  }
  bool unmasked = (ms == 0.f);
  rnm[i] = unmasked ? (1.f / fmaxf(nv, 1e-4f)) : __uint_as_float(0x7fc00000u);
  if (!unmasked) atomicAdd(&zb[bb], 1);
}

// ---------- transpose b to pixel-major b_t[bb][pix][c] (for gather) ----------
__global__ __launch_bounds__(256) void k_btrans(const float* __restrict__ b,
                                                float* __restrict__ bt) {
  __shared__ float tile[32][33];
  int bb = blockIdx.z;
  int c0 = blockIdx.y * 32;
  int p0 = blockIdx.x * 32;
  int tx = threadIdx.x & 31, ty = threadIdx.x >> 5;
  const float* bp = b + (size_t)bb*NC*NPIX;
  #pragma unroll
  for (int r = 0; r < 32; r += 8)
    tile[r + ty][tx] = bp[(size_t)(c0 + r + ty)*NPIX + p0 + tx];
  __syncthreads();
  float* btp = bt + (size_t)bb*NPIX*NC;
  #pragma unroll
  for (int r = 0; r < 32; r += 8)
    btp[(size_t)(p0 + r + ty)*NC + c0 + tx] = tile[tx][r + ty];
}

// ---------- transpose fd,bd to pixel-major: bf16 (GEMM) + fp32 (rescore) ----------
__global__ __launch_bounds__(256) void k_fbtrans(const float* __restrict__ fd,
    const float* __restrict__ bd, unsigned short* __restrict__ fdt,
    unsigned short* __restrict__ bdt, float* __restrict__ fdp,
    float* __restrict__ bdp) {
  __shared__ float tf[32][33], tb[32][33];
  int bb = blockIdx.z;
  int c0 = blockIdx.y * 32;
  int p0 = blockIdx.x * 32;
  int tx = threadIdx.x & 31, ty = threadIdx.x >> 5;
  const float* fp = fd + (size_t)bb*NC*NL;
  const float* bp = bd + (size_t)bb*NC*NL;
  #pragma unroll
  for (int r = 0; r < 32; r += 8) {
    tf[r + ty][tx] = fp[(size_t)(c0 + r + ty)*NL + p0 + tx];
    tb[r + ty][tx] = bp[(size_t)(c0 + r + ty)*NL + p0 + tx];
  }
  __syncthreads();
  #pragma unroll
  for (int r = 0; r < 32; r += 8) {
    float fv = tf[tx][r + ty];
    float bv = tb[tx][r + ty];
    size_t idx = ((size_t)bb*NL + p0 + r + ty)*NC + c0 + tx;
    fdt[idx] = f2bf(fv);
    bdt[idx] = f2bf(bv);
    fdp[idx] = fv;
    bdp[idx] = bv;
  }
}

// ---------- pixel-dot GEMM: D[p][l] = bf16(<fd_pix(p), bd_pix(l)>), K=128 ----------
__global__ __launch_bounds__(256) void k_gemmD(
    const unsigned short* __restrict__ A, const unsigned short* __restrict__ B,
    unsigned short* __restrict__ D) {
  __shared__ __align__(16) unsigned short As[128*32];
  __shared__ __align__(16) unsigned short Bs[128*32];
  int t = threadIdx.x;
  int w = t >> 6, l = t & 63;
  int by = blockIdx.y, bx = blockIdx.x;
  int wr = w >> 1, wc = w & 1;
  f32x4 acc[4][4] = {};
  int aoff[4], boff[4];
  #pragma unroll
  for (int m = 0; m < 4; ++m) {
    aoff[m] = ((wr*64 + m*16 + (l & 15)) * 32 + ((l >> 4) * 8)) * 2;
    boff[m] = ((wc*64 + m*16 + (l & 15)) * 32 + ((l >> 4) * 8)) * 2;
  }
  const char* Ab = (const char*)A;
  const char* Bb = (const char*)B;
  char* AsB = (char*)As;
  char* BsB = (char*)Bs;
  int off = (w*2) * 1024 + l * 16;
  int r0 = off >> 6, cb0 = off & 63;
  int off1 = off + 1024;
  int r1 = off1 >> 6, cb1 = off1 & 63;
  for (int k0 = 0; k0 < 128; k0 += 32) {
    gload_lds16(Ab + ((size_t)(by*128 + r0) * 128 + k0) * 2 + cb0, AsB + (w*2+0)*1024);
    gload_lds16(Ab + ((size_t)(by*128 + r1) * 128 + k0) * 2 + cb1, AsB + (w*2+1)*1024);
    gload_lds16(Bb + ((size_t)(bx*128 + r0) * 128 + k0) * 2 + cb0, BsB + (w*2+0)*1024);
    gload_lds16(Bb + ((size_t)(bx*128 + r1) * 128 + k0) * 2 + cb1, BsB + (w*2+1)*1024);
    __syncthreads();
    s16x8 af[4], bf[4];
    #pragma unroll
    for (int m = 0; m < 4; ++m) af[m] = *(const s16x8*)(AsB + aoff[m]);
    #pragma unroll
    for (int n = 0; n < 4; ++n) bf[n] = *(const s16x8*)(BsB + boff[n]);
    #pragma unroll
    for (int m = 0; m < 4; ++m)
      #pragma unroll
      for (int n = 0; n < 4; ++n)
        acc[m][n] = __builtin_amdgcn_mfma_f32_16x16x32_bf16(af[m], bf[n], acc[m][n], 0, 0, 0);
    __syncthreads();
  }
  int cr = l >> 4;
  int cc = l & 15;
  #pragma unroll
  for (int n = 0; n < 4; ++n) {
    int col = bx*128 + wc*64 + n*16 + cc;
    #pragma unroll
    for (int m = 0; m < 4; ++m) {
      int grow = by*128 + wr*64 + m*16 + cr*4;
      #pragma unroll
      for (int j = 0; j < 4; ++j)
        D[(size_t)(grow + j) * NL + col] = f2bf(acc[m][n][j]);
    }
  }
}

// ---------- horizontal pass: E[p][l] = sum_dw D[p+dw][l+dw], register-shifted ----------
__global__ __launch_bounds__(256) void k_hpass(const unsigned short* __restrict__ D,
                                               unsigned short* __restrict__ E) {
  int p = blockIdx.x;
  int px = p & 63;
  int t = threadIdx.x;
  bool okm = px > 0, okp = px < 63;
  const unsigned short* r0 = D + (size_t)p*NL;
  const unsigned short* rm = D + (size_t)(okm ? p-1 : p)*NL;
  const unsigned short* rp = D + (size_t)(okp ? p+1 : p)*NL;
  #pragma unroll
  for (int ch = 0; ch < 2; ++ch) {
    int l0 = (ch*256 + t) * 8;
    uint4 b0 = *(const uint4*)(r0 + l0);
    int lam = l0 ? (l0 - 8) : 0;
    uint4 am = *(const uint4*)(rm + lam);
    uint4 bm = *(const uint4*)(rm + l0);
    uint4 bp = *(const uint4*)(rp + l0);
    int lcp = (l0 < NL - 8) ? (l0 + 8) : l0;
    uint4 cp = *(const uint4*)(rp + lcp);
    unsigned bmu[4] = {bm.x, bm.y, bm.z, bm.w};
    unsigned bpu[4] = {bp.x, bp.y, bp.z, bp.w};
    unsigned b0u[4] = {b0.x, b0.y, b0.z, b0.w};
    unsigned sm[4], sp[4];
    sm[0] = (am.w >> 16) | (bmu[0] << 16);
    sm[1] = (bmu[0] >> 16) | (bmu[1] << 16);
    sm[2] = (bmu[1] >> 16) | (bmu[2] << 16);
    sm[3] = (bmu[2] >> 16) | (bmu[3] << 16);
    sp[0] = (bpu[0] >> 16) | (bpu[1] << 16);
    sp[1] = (bpu[1] >> 16) | (bpu[2] << 16);
    sp[2] = (bpu[2] >> 16) | (bpu[3] << 16);
    sp[3] = (bpu[3] >> 16) | (cp.x << 16);
    unsigned eo[4];
    #pragma unroll
    for (int k = 0; k < 4; ++k) {
      int j0 = 2*k;
      int lx0 = (l0 + j0) & 63;
      float v0 = (okm && lx0 > 0) ? bf2f((unsigned short)(sm[k] & 0xffffu)) : 0.f;
      v0 += bf2f((unsigned short)(b0u[k] & 0xffffu));
      v0 += (okp && lx0 < 63) ? bf2f((unsigned short)(sp[k] & 0xffffu)) : 0.f;
      int lx1 = (l0 + j0 + 1) & 63;
      float v1 = (okm && lx1 > 0) ? bf2f((unsigned short)(sm[k] >> 16)) : 0.f;
      v1 += bf2f((unsigned short)(b0u[k] >> 16));
      v1 += (okp && lx1 < 63) ? bf2f((unsigned short)(sp[k] >> 16)) : 0.f;
      eo[k] = (unsigned)f2bf(v0) | ((unsigned)f2bf(v1) << 16);
    }
    uint4 outv; outv.x = eo[0]; outv.y = eo[1]; outv.z = eo[2]; outv.w = eo[3];
    *(uint4*)(E + (size_t)p*NL + l0) = outv;
  }
}

// ---------- wave-per-row: single-pass stencil + rowmax + collect + exact rescore ----------
// 4 waves/block, wave w owns row p. s-values kept in registers as packed bf16.
__global__ __launch_bounds__(256) void k_rescore5(const unsigned short* __restrict__ E,
    const float* __restrict__ rnm, const float* __restrict__ fdp,
    const float* __restrict__ bdp, const float* __restrict__ nrm,
    const int* __restrict__ zb, int* __restrict__ cnt, Ent* __restrict__ ent,
    float* __restrict__ ooff, int bb) {
  __shared__ float fpat_s[4][1152];   // [r][c] per wave
  __shared__ int   cl_s[4][MAXC];
  __shared__ float cs_s[4][MAXC];
  __shared__ int   cnt_s[4];
  int t = threadIdx.x;
  int w = t >> 6, lane = t & 63;
  int p = blockIdx.x * 4 + w;
  int py = p >> 6;
  int ihp = py, iwp = p & 63;
  float* fpat = fpat_s[w];
  int* cl = cl_s[w];
  float* cs = cs_s[w];
  const float* fdpb = fdp + (size_t)bb*NL*NC;
  const float* bdpb = bdp + (size_t)bb*NL*NC;
  const float* rb = rnm + bb*NL;
  const float* nb = nrm + bb*NL;
  if (lane == 0) cnt_s[w] = 0;

  // stage fpat: 9 iterations of float2 (coalesced 512 B), layout [r*128+c]
  #pragma unroll
  for (int r = 0; r < 9; ++r) {
    int y = ihp + r/3 - 1, x = iwp + (r % 3) - 1;
    bool ok = ((unsigned)y < 64u) && ((unsigned)x < 64u);
    float2 v = ok ? *(const float2*)(fdpb + (size_t)(y*WD + x)*NC + lane*2)
                  : make_float2(0.f, 0.f);
    fpat[r*128 + lane*2]     = v.x;
    fpat[r*128 + lane*2 + 1] = v.y;
  }

  // single pass: compute s (fp32), track max, keep packed-bf16 copies in registers
  unsigned spk[8][4];
  float mx = -3e38f;
  #pragma unroll
  for (int j = 0; j < 8; ++j) {
    int cb = j*512 + lane*8;
    int ly = cb >> 6;
    bool okm = (py > 0) && (ly > 0);
    bool okp = (py < 63) && (ly < 63);
    size_t a0 = (size_t)p*NL + cb;
    uint4 e0 = *(const uint4*)(E + a0);
    uint4 em = *(const uint4*)(E + (okm ? ((size_t)(p-64)*NL + cb - 64) : a0));
    uint4 ep = *(const uint4*)(E + (okp ? ((size_t)(p+64)*NL + cb + 64) : a0));
    float4 r0 = *(const float4*)(rb + cb);
    float4 r1 = *(const float4*)(rb + cb + 4);
    unsigned e0u[4] = {e0.x,e0.y,e0.z,e0.w};
    unsigned emu[4] = {em.x,em.y,em.z,em.w};
    unsigned epu[4] = {ep.x,ep.y,ep.z,ep.w};
    float rr8[8] = {r0.x,r0.y,r0.z,r0.w,r1.x,r1.y,r1.z,r1.w};
    #pragma unroll
    for (int k = 0; k < 4; ++k) {
      float v0 = okm ? bf2f((unsigned short)(emu[k] & 0xffffu)) : 0.f;
      v0 += bf2f((unsigned short)(e0u[k] & 0xffffu));
      v0 += okp ? bf2f((unsigned short)(epu[k] & 0xffffu)) : 0.f;
      float v1 = okm ? bf2f((unsigned short)(emu[k] >> 16)) : 0.f;
      v1 += bf2f((unsigned short)(e0u[k] >> 16));
      v1 += okp ? bf2f((unsigned short)(epu[k] >> 16)) : 0.f;
      float s0 = v0 * rr8[2*k];          // NaN when masked
      float s1 = v1 * rr8[2*k+1];
      mx = fmaxf(mx, s0);                // fmaxf ignores NaN
      mx = fmaxf(mx, s1);
      spk[j][k] = (unsigned)f2bf(s0) | ((unsigned)f2bf(s1) << 16);
    }
  }
  #pragma unroll
  for (int o = 32; o > 0; o >>= 1) mx = fmaxf(mx, __shfl_xor(mx, o, 64));
  float thr = mx - CUTS;

  // collect candidates from registers (NaN >= thr is false)
  #pragma unroll
  for (int j = 0; j < 8; ++j) {
    int cb = j*512 + lane*8;
    #pragma unroll
    for (int k = 0; k < 4; ++k) {
      float s0 = bf2f((unsigned short)(spk[j][k] & 0xffffu));
      float s1 = bf2f((unsigned short)(spk[j][k] >> 16));
      if (s0 >= thr) {
        int slot = atomicAdd(&cnt_s[w], 1);
        if (slot < MAXC) cl[slot] = cb + 2*k;
      }
      if (s1 >= thr) {
        int slot = atomicAdd(&cnt_s[w], 1);
        if (slot < MAXC) cl[slot] = cb + 2*k + 1;
      }
    }
  }
  int nc = cnt_s[w];           // wave-synchronous: atomics complete within wave
  nc = __shfl(nc, 0, 64);
  nc = nc < MAXC ? nc : MAXC;
  if (lane == 0 && nc > 1) {   // deterministic order: sort candidates by l
    for (int a = 1; a < nc; ++a) {
      int v = cl[a]; int q = a - 1;
      while (q >= 0 && cl[q] > v) { cl[q+1] = cl[q]; --q; }
      cl[q+1] = v;
    }
  }
  // exact fp32 dot per candidate: lane = channel pair (coalesced)
  for (int a = 0; a < nc; ++a) {
    int lidx = cl[a];
    int ph = lidx >> 6, pw = lidx & 63;
    float sum = 0.f;
    #pragma unroll
    for (int r = 0; r < 9; ++r) {
      int y = ph + r/3 - 1, x = pw + (r % 3) - 1;
      bool ok = ((unsigned)y < 64u) && ((unsigned)x < 64u);
      const float* brow = bdpb + (size_t)(y*WD + x)*NC;
      float b0 = ok ? brow[lane] : 0.f;
      float b1 = ok ? brow[lane + 64] : 0.f;
      sum = fmaf(fpat[r*128 + lane], b0, sum);
      sum = fmaf(fpat[r*128 + lane + 64], b1, sum);
    }
    #pragma unroll
    for (int o = 32; o > 0; o >>= 1) sum += __shfl_xor(sum, o, 64);
    if (lane == 0) cs[a] = sum / fmaxf(nb[lidx], 1e-4f);
  }
  if (lane == 0) {
    float smax = -3e38f; int sidx = 0x7fffffff;
    for (int a = 0; a < nc; ++a)
      if (cs[a] > smax) { smax = cs[a]; sidx = cl[a]; }   // sorted by l
    int Z = zb[bb];
    size_t base = (size_t)(bb*NL + p) * MAXENT;
    if (nc == 0) {
      cnt[bb*NL + p] = 0;
      ooff[((bb*2 + 0)*HD + ihp)*WD + iwp] = (float)(0 - ihp);
      ooff[((bb*2 + 1)*HD + ihp)*WD + iwp] = (float)(0 - iwp);
    } else {
      float xm = smax * SM_SCALE;
      if (Z > 0) xm = fmaxf(xm, 0.f);
      float den = 0.f;
      for (int a = 0; a < nc; ++a) {
        float d = cs[a] * SM_SCALE - xm;
        if (d > -CUT) den += expf(d);
      }
      if (Z > 0 && -xm > -CUT) den += (float)Z * expf(-xm);
      int n = 0;
      for (int a = 0; a < nc && n < MAXENT; ++a) {
        float d = cs[a] * SM_SCALE - xm;
        if (d > -CUT) { ent[base + n].l = cl[a]; ent[base + n].p = expf(d) / den; ++n; }
      }
      cnt[bb*NL + p] = n;
      ooff[((bb*2 + 0)*HD + ihp)*WD + iwp] = (float)((sidx >> 6) - ihp);
      ooff[((bb*2 + 1)*HD + ihp)*WD + iwp] = (float)((sidx & 63) - iwp);
    }
  }
}

// ---------- plan: per output pixel, channel-independent contribution list ----------
__global__ void k_plan(const int* __restrict__ cnt, const Ent* __restrict__ ent,
                       int* __restrict__ npl, int* __restrict__ offs,
                       float* __restrict__ wts) {
  int i = blockIdx.x * blockDim.x + threadIdx.x;
  if (i >= NB*NPIX) return;
  int pix = i & (NPIX-1); int bb = i >> 14;
  int oh = pix >> 7, ow = pix & 127;
  int ihlo = (oh - 1) >> 1;
  int iwlo = (ow - 1) >> 1;
  int n = 0;
  #pragma unroll
  for (int a = 0; a < 2; ++a) {
    int ih = ihlo + a;
    if ((unsigned)ih >= 64u) continue;
    #pragma unroll
    for (int d = 0; d < 2; ++d) {
      int iw = iwlo + d;
      if ((unsigned)iw >= 64u) continue;
      int pidx = bb*NL + ih*WD + iw;
      int nn = cnt[pidx];
      const Ent* ep = ent + (size_t)pidx*MAXENT;
      for (int j = 0; j < nn; ++j) {
        Ent e = ep[j];
        int ph = e.l >> 6, pw = e.l & 63;
        int yy = oh + 2*(ph - ih);
        int xx = ow + 2*(pw - iw);
        if ((unsigned)yy < 128u && (unsigned)xx < 128u) {
          offs[((size_t)bb*PLMAX + n)*NPIX + pix] = yy*NW + xx;
          wts[((size_t)bb*PLMAX + n)*NPIX + pix] = e.p;
          ++n;
        }
      }
    }
  }
  npl[i] = n;
}

// ---------- gather v4: thread = (pixel, channel-quad), pixel-major bt ----------
__global__ __launch_bounds__(256) void k_gather4(const float* __restrict__ bt,
    const int* __restrict__ npl, const int* __restrict__ offs,
    const float* __restrict__ wts, float* __restrict__ yout) {
  __shared__ float sm[8][132];
  int bb = blockIdx.y;
  int pixbase = blockIdx.x * 8;
  int t = threadIdx.x;
  int g = t & 31, pl = t >> 5;
  int c0 = g * 4;
  int pix = pixbase + pl;
  const float* btb = bt + (size_t)bb*NPIX*NC;
  int n = npl[bb*NPIX + pix];
  float ax = 0.f, ay = 0.f, az = 0.f, aw = 0.f;
  for (int j = 0; j < n; ++j) {
    int off = offs[((size_t)bb*PLMAX + j)*NPIX + pix];
    float wv = wts[((size_t)bb*PLMAX + j)*NPIX + pix];
    float4 v = *(const float4*)(btb + (size_t)off*NC + c0);
    ax = fmaf(wv, v.x, ax); ay = fmaf(wv, v.y, ay);
    az = fmaf(wv, v.z, az); aw = fmaf(wv, v.w, aw);
  }
  sm[pl][c0+0] = ax; sm[pl][c0+1] = ay; sm[pl][c0+2] = az; sm[pl][c0+3] = aw;
  __syncthreads();
  #pragma unroll
  for (int k = 0; k < 4; ++k) {
    int c = (t >> 3) + 32*k;
    int i = t & 7;
    yout[((size_t)bb*NC + c)*NPIX + pixbase + i] = sm[i][c] * 0.25f;
  }
}

extern "C" void kernel_launch(void* const* d_in, const int* in_sizes, int n_in,
                              void* d_out, int out_size, void* d_ws, size_t ws_size,
                              hipStream_t stream) {
  const float* f = (const float*)d_in[0];
  const float* b = (const float*)d_in[1];
  const float* mask = (const float*)d_in[2];
  float* out = (float*)d_out;

  char* w = (char*)d_ws;
  float* fd   = (float*)w;  w += (size_t)NB*NC*HD*WD*4;
  float* bd   = (float*)w;  w += (size_t)NB*NC*HD*WD*4;
  double* sq  = (double*)w; w += (size_t)NB*HD*WD*8;
  float* norm = (float*)w;  w += (size_t)NB*NL*4;
  float* rnm  = (float*)w;  w += (size_t)NB*NL*4;
  int* cnt    = (int*)w;    w += (size_t)NB*NL*4;
  Ent* ent    = (Ent*)w;    w += (size_t)NB*NL*MAXENT*sizeof(Ent);
  unsigned short* fdt = (unsigned short*)w; w += (size_t)NB*NL*NC*2;
  unsigned short* bdt = (unsigned short*)w; w += (size_t)NB*NL*NC*2;
  float* fdp  = (float*)w;  w += (size_t)NB*NL*NC*4;
  float* bdp  = (float*)w;  w += (size_t)NB*NL*NC*4;
  int* zb     = (int*)w;    w += 64;
  int* npl    = (int*)w;    w += (size_t)NB*NPIX*4;
  int* offs   = (int*)w;    w += (size_t)NB*PLMAX*NPIX*4;
  float* wts  = (float*)w;  w += (size_t)NB*PLMAX*NPIX*4;
  // D (32 MB, in-loop) aliases bt (33.5 MB, post-loop)
  float* bt   = (float*)w;
  unsigned short* D = (unsigned short*)w; w += (size_t)NB*NPIX*NC*4;
  unsigned short* E = (unsigned short*)w;   // 32 MB, reused per batch

  int n1 = NB*NC*HD*WD;
  k_prep<<<(n1+255)/256, 256, 0, stream>>>(f, b, fd, bd);
  k_sq<<<(NB*HD*WD+255)/256, 256, 0, stream>>>(bd, sq);
  hipMemsetAsync(zb, 0, 64, stream);
  k_normmm<<<(NB*NL+255)/256, 256, 0, stream>>>(sq, mask, norm, rnm, zb);
  k_fbtrans<<<dim3(NL/32, NC/32, NB), 256, 0, stream>>>(fd, bd, fdt, bdt, fdp, bdp);

  float* ooff = out + (size_t)NB*NC*NH*NW;
  for (int bb = 0; bb < NB; ++bb) {
    k_gemmD<<<dim3(32, 32), 256, 0, stream>>>(fdt + (size_t)bb*NL*NC,
                                              bdt + (size_t)bb*NL*NC, D);
    k_hpass<<<NL, 256, 0, stream>>>(D, E);
    k_rescore5<<<NL/4, 256, 0, stream>>>(E, rnm, fdp, bdp, norm, zb, cnt, ent, ooff, bb);
  }
  k_btrans<<<dim3(NPIX/32, NC/32, NB), 256, 0, stream>>>(b, bt);
  k_plan<<<(NB*NPIX+255)/256, 256, 0, stream>>>(cnt, ent, npl, offs, wts);
  k_gather4<<<dim3(NPIX/8, NB), 256, 0, stream>>>(bt, npl, offs, wts, out);
}

// Round 13
// 313.269 us; speedup vs baseline: 1.2931x; 1.0265x over previous
//
#include <hip/hip_runtime.h>
#include <cmath>

#define NB 4
#define NC 128
#define NH 128
#define NW 128
#define HD 64
#define WD 64
#define NL 4096      // 64*64 positions / patches
#define NPIX 16384   // 128*128 output pixels per batch
#define SM_SCALE 2550.0f
#define CUT 40.0f
#define CUTS 0.216f  // candidate margin in score units
#define MAXENT 8
#define MAXC 256
#define PLMAX 32     // 4 positions x MAXENT survivors

struct Ent { int l; float p; };

typedef __attribute__((ext_vector_type(4))) float f32x4;
typedef __attribute__((ext_vector_type(8))) short s16x8;

__device__ __forceinline__ unsigned short f2bf(float x) {
  unsigned u = __float_as_uint(x);
  return (unsigned short)((u + 0x7fffu + ((u >> 16) & 1u)) >> 16);
}
__device__ __forceinline__ float bf2f(unsigned short h) {
  return __uint_as_float(((unsigned)h) << 16);
}
__device__ __forceinline__ void gload_lds16(const void* g, void* l) {
  __builtin_amdgcn_global_load_lds(
      (const __attribute__((address_space(1))) void*)g,
      (__attribute__((address_space(3))) void*)l, 16, 0, 0);
}

// ---------- prep ----------
__global__ void k_prep(const float* __restrict__ f, const float* __restrict__ b,
                       float* __restrict__ fd, float* __restrict__ bd) {
  int i = blockIdx.x * blockDim.x + threadIdx.x;
  if (i >= NB*NC*HD*WD) return;
  int x = i & 63, y = (i >> 6) & 63, c = (i >> 12) & 127, bb = i >> 19;
  int src = ((bb*NC + c)*NH + 2*y)*NW + 2*x;
  fd[i] = f[src];
  bd[i] = b[src];
}

__global__ void k_sq(const float* __restrict__ bd, double* __restrict__ sq) {
  int i = blockIdx.x * blockDim.x + threadIdx.x;
  if (i >= NB*HD*WD) return;
  int x = i & 63, y = (i >> 6) & 63, bb = i >> 12;
  double s = 0.0;
  const float* p = bd + (size_t)bb*NC*HD*WD + y*WD + x;
  for (int c = 0; c < NC; ++c) {
    double v = (double)p[(size_t)c*HD*WD];
    s += v*v;
  }
  sq[i] = s;
}

// norm, masked reciprocal (NaN when masked), zero-count
__global__ void k_normmm(const double* __restrict__ sq, const float* __restrict__ mask,
                         float* __restrict__ norm, float* __restrict__ rnm,
                         int* __restrict__ zb) {
  int i = blockIdx.x * blockDim.x + threadIdx.x;
  if (i >= NB*NL) return;
  int pw = i & 63, ph = (i >> 6) & 63, bb = i >> 12;
  double s = 0.0;
  for (int dh = -1; dh <= 1; ++dh) {
    int y = ph + dh; if ((unsigned)y >= 64u) continue;
    for (int dw = -1; dw <= 1; ++dw) {
      int x = pw + dw; if ((unsigned)x >= 64u) continue;
      s += sq[(bb*HD + y)*WD + x];
    }
  }
  float nv = (float)sqrt(s);
  norm[i] = nv;
  float ms = 0.f;
  const float* mb = mask + (size_t)bb*512*512;
  for (int dh = -1; dh <= 1; ++dh) {
    int y = ph + dh; if ((unsigned)y >= 64u) continue;
    for (int dw = -1; dw <= 1; ++dw) {
      int x = pw + dw; if ((unsigned)x >= 64u) continue;
      ms += mb[(y*8)*512 + x*8];
    }
  }
  bool unmasked = (ms == 0.f);
  rnm[i] = unmasked ? (1.f / fmaxf(nv, 1e-4f)) : __uint_as_float(0x7fc00000u);
  if (!unmasked) atomicAdd(&zb[bb], 1);
}

// ---------- transpose b to pixel-major b_t[bb][pix][c] (for gather) ----------
__global__ __launch_bounds__(256) void k_btrans(const float* __restrict__ b,
                                                float* __restrict__ bt) {
  __shared__ float tile[32][33];
  int bb = blockIdx.z;
  int c0 = blockIdx.y * 32;
  int p0 = blockIdx.x * 32;
  int tx = threadIdx.x & 31, ty = threadIdx.x >> 5;
  const float* bp = b + (size_t)bb*NC*NPIX;
  #pragma unroll
  for (int r = 0; r < 32; r += 8)
    tile[r + ty][tx] = bp[(size_t)(c0 + r + ty)*NPIX + p0 + tx];
  __syncthreads();
  float* btp = bt + (size_t)bb*NPIX*NC;
  #pragma unroll
  for (int r = 0; r < 32; r += 8)
    btp[(size_t)(p0 + r + ty)*NC + c0 + tx] = tile[tx][r + ty];
}

// ---------- transpose fd,bd to pixel-major: bf16 (GEMM) + fp32 (rescore) ----------
__global__ __launch_bounds__(256) void k_fbtrans(const float* __restrict__ fd,
    const float* __restrict__ bd, unsigned short* __restrict__ fdt,
    unsigned short* __restrict__ bdt, float* __restrict__ fdp,
    float* __restrict__ bdp) {
  __shared__ float tf[32][33], tb[32][33];
  int bb = blockIdx.z;
  int c0 = blockIdx.y * 32;
  int p0 = blockIdx.x * 32;
  int tx = threadIdx.x & 31, ty = threadIdx.x >> 5;
  const float* fp = fd + (size_t)bb*NC*NL;
  const float* bp = bd + (size_t)bb*NC*NL;
  #pragma unroll
  for (int r = 0; r < 32; r += 8) {
    tf[r + ty][tx] = fp[(size_t)(c0 + r + ty)*NL + p0 + tx];
    tb[r + ty][tx] = bp[(size_t)(c0 + r + ty)*NL + p0 + tx];
  }
  __syncthreads();
  #pragma unroll
  for (int r = 0; r < 32; r += 8) {
    float fv = tf[tx][r + ty];
    float bv = tb[tx][r + ty];
    size_t idx = ((size_t)bb*NL + p0 + r + ty)*NC + c0 + tx;
    fdt[idx] = f2bf(fv);
    bdt[idx] = f2bf(bv);
    fdp[idx] = fv;
    bdp[idx] = bv;
  }
}

// ---------- pixel-dot GEMM: D[p][l] = bf16(<fd_pix(p), bd_pix(l)>), K=128 ----------
// bbFixed >= 0: per-batch launch (D stride 0); bbFixed < 0: batched via blockIdx.z.
__global__ __launch_bounds__(256) void k_gemmD(
    const unsigned short* __restrict__ A, const unsigned short* __restrict__ B,
    unsigned short* __restrict__ Dall, size_t dStride, int bbFixed) {
  __shared__ __align__(16) unsigned short As[128*32];
  __shared__ __align__(16) unsigned short Bs[128*32];
  int bb = (bbFixed >= 0) ? bbFixed : blockIdx.z;
  const unsigned short* Abase = A + (size_t)bb*NL*NC;
  const unsigned short* Bbase = B + (size_t)bb*NL*NC;
  unsigned short* D = Dall + (size_t)(bbFixed >= 0 ? 0 : bb) * dStride;
  int t = threadIdx.x;
  int w = t >> 6, l = t & 63;
  int by = blockIdx.y, bx = blockIdx.x;
  int wr = w >> 1, wc = w & 1;
  f32x4 acc[4][4] = {};
  int aoff[4], boff[4];
  #pragma unroll
  for (int m = 0; m < 4; ++m) {
    aoff[m] = ((wr*64 + m*16 + (l & 15)) * 32 + ((l >> 4) * 8)) * 2;
    boff[m] = ((wc*64 + m*16 + (l & 15)) * 32 + ((l >> 4) * 8)) * 2;
  }
  const char* Ab = (const char*)Abase;
  const char* Bb = (const char*)Bbase;
  char* AsB = (char*)As;
  char* BsB = (char*)Bs;
  int off = (w*2) * 1024 + l * 16;
  int r0 = off >> 6, cb0 = off & 63;
  int off1 = off + 1024;
  int r1 = off1 >> 6, cb1 = off1 & 63;
  for (int k0 = 0; k0 < 128; k0 += 32) {
    gload_lds16(Ab + ((size_t)(by*128 + r0) * 128 + k0) * 2 + cb0, AsB + (w*2+0)*1024);
    gload_lds16(Ab + ((size_t)(by*128 + r1) * 128 + k0) * 2 + cb1, AsB + (w*2+1)*1024);
    gload_lds16(Bb + ((size_t)(bx*128 + r0) * 128 + k0) * 2 + cb0, BsB + (w*2+0)*1024);
    gload_lds16(Bb + ((size_t)(bx*128 + r1) * 128 + k0) * 2 + cb1, BsB + (w*2+1)*1024);
    __syncthreads();
    s16x8 af[4], bf[4];
    #pragma unroll
    for (int m = 0; m < 4; ++m) af[m] = *(const s16x8*)(AsB + aoff[m]);
    #pragma unroll
    for (int n = 0; n < 4; ++n) bf[n] = *(const s16x8*)(BsB + boff[n]);
    #pragma unroll
    for (int m = 0; m < 4; ++m)
      #pragma unroll
      for (int n = 0; n < 4; ++n)
        acc[m][n] = __builtin_amdgcn_mfma_f32_16x16x32_bf16(af[m], bf[n], acc[m][n], 0, 0, 0);
    __syncthreads();
  }
  int cr = l >> 4;
  int cc = l & 15;
  #pragma unroll
  for (int n = 0; n < 4; ++n) {
    int col = bx*128 + wc*64 + n*16 + cc;
    #pragma unroll
    for (int m = 0; m < 4; ++m) {
      int grow = by*128 + wr*64 + m*16 + cr*4;
      #pragma unroll
      for (int j = 0; j < 4; ++j)
        D[(size_t)(grow + j) * NL + col] = f2bf(acc[m][n][j]);
    }
  }
}

// ---------- horizontal pass: E[p][l] = sum_dw D[p+dw][l+dw], register-shifted ----------
__global__ __launch_bounds__(256) void k_hpass(const unsigned short* __restrict__ Dall,
                                               unsigned short* __restrict__ Eall,
                                               size_t stride, int bbFixed) {
  int bb = (bbFixed >= 0) ? bbFixed : blockIdx.y;
  size_t soff = (size_t)(bbFixed >= 0 ? 0 : bb) * stride;
  const unsigned short* D = Dall + soff;
  unsigned short* E = Eall + soff;
  int p = blockIdx.x;
  int px = p & 63;
  int t = threadIdx.x;
  bool okm = px > 0, okp = px < 63;
  const unsigned short* r0 = D + (size_t)p*NL;
  const unsigned short* rm = D + (size_t)(okm ? p-1 : p)*NL;
  const unsigned short* rp = D + (size_t)(okp ? p+1 : p)*NL;
  #pragma unroll
  for (int ch = 0; ch < 2; ++ch) {
    int l0 = (ch*256 + t) * 8;
    uint4 b0 = *(const uint4*)(r0 + l0);
    int lam = l0 ? (l0 - 8) : 0;
    uint4 am = *(const uint4*)(rm + lam);
    uint4 bm = *(const uint4*)(rm + l0);
    uint4 bp = *(const uint4*)(rp + l0);
    int lcp = (l0 < NL - 8) ? (l0 + 8) : l0;
    uint4 cp = *(const uint4*)(rp + lcp);
    unsigned bmu[4] = {bm.x, bm.y, bm.z, bm.w};
    unsigned bpu[4] = {bp.x, bp.y, bp.z, bp.w};
    unsigned b0u[4] = {b0.x, b0.y, b0.z, b0.w};
    unsigned sm[4], sp[4];
    sm[0] = (am.w >> 16) | (bmu[0] << 16);
    sm[1] = (bmu[0] >> 16) | (bmu[1] << 16);
    sm[2] = (bmu[1] >> 16) | (bmu[2] << 16);
    sm[3] = (bmu[2] >> 16) | (bmu[3] << 16);
    sp[0] = (bpu[0] >> 16) | (bpu[1] << 16);
    sp[1] = (bpu[1] >> 16) | (bpu[2] << 16);
    sp[2] = (bpu[2] >> 16) | (bpu[3] << 16);
    sp[3] = (bpu[3] >> 16) | (cp.x << 16);
    unsigned eo[4];
    #pragma unroll
    for (int k = 0; k < 4; ++k) {
      int j0 = 2*k;
      int lx0 = (l0 + j0) & 63;
      float v0 = (okm && lx0 > 0) ? bf2f((unsigned short)(sm[k] & 0xffffu)) : 0.f;
      v0 += bf2f((unsigned short)(b0u[k] & 0xffffu));
      v0 += (okp && lx0 < 63) ? bf2f((unsigned short)(sp[k] & 0xffffu)) : 0.f;
      int lx1 = (l0 + j0 + 1) & 63;
      float v1 = (okm && lx1 > 0) ? bf2f((unsigned short)(sm[k] >> 16)) : 0.f;
      v1 += bf2f((unsigned short)(b0u[k] >> 16));
      v1 += (okp && lx1 < 63) ? bf2f((unsigned short)(sp[k] >> 16)) : 0.f;
      eo[k] = (unsigned)f2bf(v0) | ((unsigned)f2bf(v1) << 16);
    }
    uint4 outv; outv.x = eo[0]; outv.y = eo[1]; outv.z = eo[2]; outv.w = eo[3];
    *(uint4*)(E + (size_t)p*NL + l0) = outv;
  }
}

// ---------- wave-per-row: single-pass stencil + rowmax + collect + exact rescore ----------
__global__ __launch_bounds__(256) void k_rescore5(const unsigned short* __restrict__ Eall,
    size_t eStride, const float* __restrict__ rnm, const float* __restrict__ fdp,
    const float* __restrict__ bdp, const float* __restrict__ nrm,
    const int* __restrict__ zb, int* __restrict__ cnt, Ent* __restrict__ ent,
    float* __restrict__ ooff, int bbFixed) {
  __shared__ float fpat_s[4][1152];   // [r][c] per wave
  __shared__ int   cl_s[4][MAXC];
  __shared__ float cs_s[4][MAXC];
  __shared__ int   cnt_s[4];
  int bb = (bbFixed >= 0) ? bbFixed : blockIdx.y;
  const unsigned short* E = Eall + (size_t)(bbFixed >= 0 ? 0 : bb) * eStride;
  int t = threadIdx.x;
  int w = t >> 6, lane = t & 63;
  int p = blockIdx.x * 4 + w;
  int py = p >> 6;
  int ihp = py, iwp = p & 63;
  float* fpat = fpat_s[w];
  int* cl = cl_s[w];
  float* cs = cs_s[w];
  const float* fdpb = fdp + (size_t)bb*NL*NC;
  const float* bdpb = bdp + (size_t)bb*NL*NC;
  const float* rb = rnm + bb*NL;
  const float* nb = nrm + bb*NL;
  if (lane == 0) cnt_s[w] = 0;

  // stage fpat: 9 iterations of float2 (coalesced 512 B), layout [r*128+c]
  #pragma unroll
  for (int r = 0; r < 9; ++r) {
    int y = ihp + r/3 - 1, x = iwp + (r % 3) - 1;
    bool ok = ((unsigned)y < 64u) && ((unsigned)x < 64u);
    float2 v = ok ? *(const float2*)(fdpb + (size_t)(y*WD + x)*NC + lane*2)
                  : make_float2(0.f, 0.f);
    fpat[r*128 + lane*2]     = v.x;
    fpat[r*128 + lane*2 + 1] = v.y;
  }

  // single pass: compute s (fp32), track max, keep packed-bf16 copies in registers
  unsigned spk[8][4];
  float mx = -3e38f;
  #pragma unroll
  for (int j = 0; j < 8; ++j) {
    int cb = j*512 + lane*8;
    int ly = cb >> 6;
    bool okm = (py > 0) && (ly > 0);
    bool okp = (py < 63) && (ly < 63);
    size_t a0 = (size_t)p*NL + cb;
    uint4 e0 = *(const uint4*)(E + a0);
    uint4 em = *(const uint4*)(E + (okm ? ((size_t)(p-64)*NL + cb - 64) : a0));
    uint4 ep = *(const uint4*)(E + (okp ? ((size_t)(p+64)*NL + cb + 64) : a0));
    float4 r0 = *(const float4*)(rb + cb);
    float4 r1 = *(const float4*)(rb + cb + 4);
    unsigned e0u[4] = {e0.x,e0.y,e0.z,e0.w};
    unsigned emu[4] = {em.x,em.y,em.z,em.w};
    unsigned epu[4] = {ep.x,ep.y,ep.z,ep.w};
    float rr8[8] = {r0.x,r0.y,r0.z,r0.w,r1.x,r1.y,r1.z,r1.w};
    #pragma unroll
    for (int k = 0; k < 4; ++k) {
      float v0 = okm ? bf2f((unsigned short)(emu[k] & 0xffffu)) : 0.f;
      v0 += bf2f((unsigned short)(e0u[k] & 0xffffu));
      v0 += okp ? bf2f((unsigned short)(epu[k] & 0xffffu)) : 0.f;
      float v1 = okm ? bf2f((unsigned short)(emu[k] >> 16)) : 0.f;
      v1 += bf2f((unsigned short)(e0u[k] >> 16));
      v1 += okp ? bf2f((unsigned short)(epu[k] >> 16)) : 0.f;
      float s0 = v0 * rr8[2*k];          // NaN when masked
      float s1 = v1 * rr8[2*k+1];
      mx = fmaxf(mx, s0);                // fmaxf ignores NaN
      mx = fmaxf(mx, s1);
      spk[j][k] = (unsigned)f2bf(s0) | ((unsigned)f2bf(s1) << 16);
    }
  }
  #pragma unroll
  for (int o = 32; o > 0; o >>= 1) mx = fmaxf(mx, __shfl_xor(mx, o, 64));
  float thr = mx - CUTS;

  // collect candidates from registers (NaN >= thr is false)
  #pragma unroll
  for (int j = 0; j < 8; ++j) {
    int cb = j*512 + lane*8;
    #pragma unroll
    for (int k = 0; k < 4; ++k) {
      float s0 = bf2f((unsigned short)(spk[j][k] & 0xffffu));
      float s1 = bf2f((unsigned short)(spk[j][k] >> 16));
      if (s0 >= thr) {
        int slot = atomicAdd(&cnt_s[w], 1);
        if (slot < MAXC) cl[slot] = cb + 2*k;
      }
      if (s1 >= thr) {
        int slot = atomicAdd(&cnt_s[w], 1);
        if (slot < MAXC) cl[slot] = cb + 2*k + 1;
      }
    }
  }
  int nc = cnt_s[w];           // wave-synchronous: atomics complete within wave
  nc = __shfl(nc, 0, 64);
  nc = nc < MAXC ? nc : MAXC;
  if (lane == 0 && nc > 1) {   // deterministic order: sort candidates by l
    for (int a = 1; a < nc; ++a) {
      int v = cl[a]; int q = a - 1;
      while (q >= 0 && cl[q] > v) { cl[q+1] = cl[q]; --q; }
      cl[q+1] = v;
    }
  }
  // exact fp32 dot per candidate: lane = channel pair (coalesced float2)
  for (int a = 0; a < nc; ++a) {
    int lidx = cl[a];
    int ph = lidx >> 6, pw = lidx & 63;
    float sum = 0.f;
    #pragma unroll
    for (int r = 0; r < 9; ++r) {
      int y = ph + r/3 - 1, x = pw + (r % 3) - 1;
      bool ok = ((unsigned)y < 64u) && ((unsigned)x < 64u);
      const float* brow = bdpb + (size_t)(y*WD + x)*NC;
      float2 bv = ok ? *(const float2*)(brow + lane*2) : make_float2(0.f, 0.f);
      sum = fmaf(fpat[r*128 + lane*2],     bv.x, sum);
      sum = fmaf(fpat[r*128 + lane*2 + 1], bv.y, sum);
    }
    #pragma unroll
    for (int o = 32; o > 0; o >>= 1) sum += __shfl_xor(sum, o, 64);
    if (lane == 0) cs[a] = sum / fmaxf(nb[lidx], 1e-4f);
  }
  if (lane == 0) {
    float smax = -3e38f; int sidx = 0x7fffffff;
    for (int a = 0; a < nc; ++a)
      if (cs[a] > smax) { smax = cs[a]; sidx = cl[a]; }   // sorted by l
    int Z = zb[bb];
    size_t base = (size_t)(bb*NL + p) * MAXENT;
    if (nc == 0) {
      cnt[bb*NL + p] = 0;
      ooff[((bb*2 + 0)*HD + ihp)*WD + iwp] = (float)(0 - ihp);
      ooff[((bb*2 + 1)*HD + ihp)*WD + iwp] = (float)(0 - iwp);
    } else {
      float xm = smax * SM_SCALE;
      if (Z > 0) xm = fmaxf(xm, 0.f);
      float den = 0.f;
      for (int a = 0; a < nc; ++a) {
        float d = cs[a] * SM_SCALE - xm;
        if (d > -CUT) den += expf(d);
      }
      if (Z > 0 && -xm > -CUT) den += (float)Z * expf(-xm);
      int n = 0;
      for (int a = 0; a < nc && n < MAXENT; ++a) {
        float d = cs[a] * SM_SCALE - xm;
        if (d > -CUT) { ent[base + n].l = cl[a]; ent[base + n].p = expf(d) / den; ++n; }
      }
      cnt[bb*NL + p] = n;
      ooff[((bb*2 + 0)*HD + ihp)*WD + iwp] = (float)((sidx >> 6) - ihp);
      ooff[((bb*2 + 1)*HD + ihp)*WD + iwp] = (float)((sidx & 63) - iwp);
    }
  }
}

// ---------- gather v5: inline plan (8 pixels/block) + pixel-major bt gather ----------
__global__ __launch_bounds__(256) void k_gather5(const float* __restrict__ bt,
    const int* __restrict__ cnt, const Ent* __restrict__ ent,
    float* __restrict__ yout) {
  __shared__ float sm[8][132];
  __shared__ int   off_s[8][PLMAX];
  __shared__ float wt_s[8][PLMAX];
  __shared__ int   n_s[8];
  int bb = blockIdx.y;
  int pixbase = blockIdx.x * 8;
  int t = threadIdx.x;
  // plan: one thread per pixel (same loop order as old k_plan -> identical order)
  if (t < 8) {
    int pix = pixbase + t;
    int oh = pix >> 7, ow = pix & 127;
    int ihlo = (oh - 1) >> 1;
    int iwlo = (ow - 1) >> 1;
    int n = 0;
    #pragma unroll
    for (int a = 0; a < 2; ++a) {
      int ih = ihlo + a;
      if ((unsigned)ih >= 64u) continue;
      #pragma unroll
      for (int d = 0; d < 2; ++d) {
        int iw = iwlo + d;
        if ((unsigned)iw >= 64u) continue;
        int pidx = bb*NL + ih*WD + iw;
        int nn = cnt[pidx];
        const Ent* ep = ent + (size_t)pidx*MAXENT;
        for (int j = 0; j < nn; ++j) {
          Ent e = ep[j];
          int ph = e.l >> 6, pw = e.l & 63;
          int yy = oh + 2*(ph - ih);
          int xx = ow + 2*(pw - iw);
          if ((unsigned)yy < 128u && (unsigned)xx < 128u) {
            off_s[t][n] = yy*NW + xx;
            wt_s[t][n] = e.p;
            ++n;
          }
        }
      }
    }
    n_s[t] = n;
  }
  __syncthreads();
  int g = t & 31, pl = t >> 5;
  int c0 = g * 4;
  const float* btb = bt + (size_t)bb*NPIX*NC;
  int n = n_s[pl];
  float ax = 0.f, ay = 0.f, az = 0.f, aw = 0.f;
  for (int j = 0; j < n; ++j) {
    int off = off_s[pl][j];
    float wv = wt_s[pl][j];
    float4 v = *(const float4*)(btb + (size_t)off*NC + c0);
    ax = fmaf(wv, v.x, ax); ay = fmaf(wv, v.y, ay);
    az = fmaf(wv, v.z, az); aw = fmaf(wv, v.w, aw);
  }
  sm[pl][c0+0] = ax; sm[pl][c0+1] = ay; sm[pl][c0+2] = az; sm[pl][c0+3] = aw;
  __syncthreads();
  #pragma unroll
  for (int k = 0; k < 4; ++k) {
    int c = (t >> 3) + 32*k;
    int i = t & 7;
    yout[((size_t)bb*NC + c)*NPIX + pixbase + i] = sm[i][c] * 0.25f;
  }
}

extern "C" void kernel_launch(void* const* d_in, const int* in_sizes, int n_in,
                              void* d_out, int out_size, void* d_ws, size_t ws_size,
                              hipStream_t stream) {
  const float* f = (const float*)d_in[0];
  const float* b = (const float*)d_in[1];
  const float* mask = (const float*)d_in[2];
  float* out = (float*)d_out;

  char* w = (char*)d_ws;
  float* fd   = (float*)w;  w += (size_t)NB*NC*HD*WD*4;
  float* bd   = (float*)w;  w += (size_t)NB*NC*HD*WD*4;
  double* sq  = (double*)w; w += (size_t)NB*HD*WD*8;
  float* norm = (float*)w;  w += (size_t)NB*NL*4;
  float* rnm  = (float*)w;  w += (size_t)NB*NL*4;
  int* cnt    = (int*)w;    w += (size_t)NB*NL*4;
  Ent* ent    = (Ent*)w;    w += (size_t)NB*NL*MAXENT*sizeof(Ent);
  unsigned short* fdt = (unsigned short*)w; w += (size_t)NB*NL*NC*2;
  unsigned short* bdt = (unsigned short*)w; w += (size_t)NB*NL*NC*2;
  float* fdp  = (float*)w;  w += (size_t)NB*NL*NC*4;
  float* bdp  = (float*)w;  w += (size_t)NB*NL*NC*4;
  int* zb     = (int*)w;    w += 64;

  size_t dBytes = (size_t)NL*NL*2;          // one batch of D or E (33.55 MB)
  size_t usedSoFar = (size_t)(w - (char*)d_ws);
  bool batched = (ws_size >= usedSoFar + 2*(size_t)NB*dBytes);

  unsigned short* D = (unsigned short*)w;   // bt aliases D (used after the loop)
  float* bt = (float*)w;
  unsigned short* E;
  if (batched) { E = (unsigned short*)(w + (size_t)NB*dBytes); }
  else         { E = (unsigned short*)(w + dBytes); }

  int n1 = NB*NC*HD*WD;
  k_prep<<<(n1+255)/256, 256, 0, stream>>>(f, b, fd, bd);
  k_sq<<<(NB*HD*WD+255)/256, 256, 0, stream>>>(bd, sq);
  hipMemsetAsync(zb, 0, 64, stream);
  k_normmm<<<(NB*NL+255)/256, 256, 0, stream>>>(sq, mask, norm, rnm, zb);
  k_fbtrans<<<dim3(NL/32, NC/32, NB), 256, 0, stream>>>(fd, bd, fdt, bdt, fdp, bdp);

  float* ooff = out + (size_t)NB*NC*NH*NW;
  if (batched) {
    k_gemmD<<<dim3(32, 32, NB), 256, 0, stream>>>(fdt, bdt, D, (size_t)NL*NL, -1);
    k_hpass<<<dim3(NL, NB), 256, 0, stream>>>(D, E, (size_t)NL*NL, -1);
    k_rescore5<<<dim3(NL/4, NB), 256, 0, stream>>>(E, (size_t)NL*NL, rnm, fdp, bdp,
                                                   norm, zb, cnt, ent, ooff, -1);
  } else {
    for (int bb = 0; bb < NB; ++bb) {
      k_gemmD<<<dim3(32, 32), 256, 0, stream>>>(fdt, bdt, D, 0, bb);
      k_hpass<<<dim3(NL), 256, 0, stream>>>(D, E, 0, bb);
      k_rescore5<<<dim3(NL/4), 256, 0, stream>>>(E, 0, rnm, fdp, bdp,
                                                 norm, zb, cnt, ent, ooff, bb);
    }
  }
  k_btrans<<<dim3(NPIX/32, NC/32, NB), 256, 0, stream>>>(b, bt);
  k_gather5<<<dim3(NPIX/8, NB), 256, 0, stream>>>(bt, cnt, ent, out);
}

// Round 14
// 201.589 us; speedup vs baseline: 2.0094x; 1.5540x over previous
//
#include <hip/hip_runtime.h>
#include <cmath>

#define NB 4
#define NC 128
#define NH 128
#define NW 128
#define HD 64
#define WD 64
#define NL 4096      // 64*64 positions / patches
#define NPIX 16384   // 128*128 output pixels per batch
#define SM_SCALE 2550.0f
#define CUT 40.0f
#define CUTS 0.216f  // candidate margin in score units
#define MAXENT 8
#define MAXC 256
#define PLMAX 32     // 4 positions x MAXENT survivors
#define DSTR 136     // Ds LDS row stride (u16), 16B-aligned rows

struct Ent { int l; float p; };

typedef __attribute__((ext_vector_type(4))) float f32x4;
typedef __attribute__((ext_vector_type(8))) short s16x8;

__device__ __forceinline__ unsigned short f2bf(float x) {
  unsigned u = __float_as_uint(x);
  return (unsigned short)((u + 0x7fffu + ((u >> 16) & 1u)) >> 16);
}
__device__ __forceinline__ float bf2f(unsigned short h) {
  return __uint_as_float(((unsigned)h) << 16);
}
__device__ __forceinline__ void gload_lds16(const void* g, void* l) {
  __builtin_amdgcn_global_load_lds(
      (const __attribute__((address_space(1))) void*)g,
      (__attribute__((address_space(3))) void*)l, 16, 0, 0);
}

// ---------- prep ----------
__global__ void k_prep(const float* __restrict__ f, const float* __restrict__ b,
                       float* __restrict__ fd, float* __restrict__ bd) {
  int i = blockIdx.x * blockDim.x + threadIdx.x;
  if (i >= NB*NC*HD*WD) return;
  int x = i & 63, y = (i >> 6) & 63, c = (i >> 12) & 127, bb = i >> 19;
  int src = ((bb*NC + c)*NH + 2*y)*NW + 2*x;
  fd[i] = f[src];
  bd[i] = b[src];
}

__global__ void k_sq(const float* __restrict__ bd, double* __restrict__ sq) {
  int i = blockIdx.x * blockDim.x + threadIdx.x;
  if (i >= NB*HD*WD) return;
  int x = i & 63, y = (i >> 6) & 63, bb = i >> 12;
  double s = 0.0;
  const float* p = bd + (size_t)bb*NC*HD*WD + y*WD + x;
  for (int c = 0; c < NC; ++c) {
    double v = (double)p[(size_t)c*HD*WD];
    s += v*v;
  }
  sq[i] = s;
}

// norm, masked reciprocal (NaN when masked), zero-count
__global__ void k_normmm(const double* __restrict__ sq, const float* __restrict__ mask,
                         float* __restrict__ norm, float* __restrict__ rnm,
                         int* __restrict__ zb) {
  int i = blockIdx.x * blockDim.x + threadIdx.x;
  if (i >= NB*NL) return;
  int pw = i & 63, ph = (i >> 6) & 63, bb = i >> 12;
  double s = 0.0;
  for (int dh = -1; dh <= 1; ++dh) {
    int y = ph + dh; if ((unsigned)y >= 64u) continue;
    for (int dw = -1; dw <= 1; ++dw) {
      int x = pw + dw; if ((unsigned)x >= 64u) continue;
      s += sq[(bb*HD + y)*WD + x];
    }
  }
  float nv = (float)sqrt(s);
  norm[i] = nv;
  float ms = 0.f;
  const float* mb = mask + (size_t)bb*512*512;
  for (int dh = -1; dh <= 1; ++dh) {
    int y = ph + dh; if ((unsigned)y >= 64u) continue;
    for (int dw = -1; dw <= 1; ++dw) {
      int x = pw + dw; if ((unsigned)x >= 64u) continue;
      ms += mb[(y*8)*512 + x*8];
    }
  }
  bool unmasked = (ms == 0.f);
  rnm[i] = unmasked ? (1.f / fmaxf(nv, 1e-4f)) : __uint_as_float(0x7fc00000u);
  if (!unmasked) atomicAdd(&zb[bb], 1);
}

// ---------- transpose b to pixel-major b_t[bb][pix][c] (for gather) ----------
__global__ __launch_bounds__(256) void k_btrans(const float* __restrict__ b,
                                                float* __restrict__ bt) {
  __shared__ float tile[32][33];
  int bb = blockIdx.z;
  int c0 = blockIdx.y * 32;
  int p0 = blockIdx.x * 32;
  int tx = threadIdx.x & 31, ty = threadIdx.x >> 5;
  const float* bp = b + (size_t)bb*NC*NPIX;
  #pragma unroll
  for (int r = 0; r < 32; r += 8)
    tile[r + ty][tx] = bp[(size_t)(c0 + r + ty)*NPIX + p0 + tx];
  __syncthreads();
  float* btp = bt + (size_t)bb*NPIX*NC;
  #pragma unroll
  for (int r = 0; r < 32; r += 8)
    btp[(size_t)(p0 + r + ty)*NC + c0 + tx] = tile[tx][r + ty];
}

// ---------- transpose fd,bd to pixel-major: bf16 (GEMM) + fp32 (rescore) ----------
__global__ __launch_bounds__(256) void k_fbtrans(const float* __restrict__ fd,
    const float* __restrict__ bd, unsigned short* __restrict__ fdt,
    unsigned short* __restrict__ bdt, float* __restrict__ fdp,
    float* __restrict__ bdp) {
  __shared__ float tf[32][33], tb[32][33];
  int bb = blockIdx.z;
  int c0 = blockIdx.y * 32;
  int p0 = blockIdx.x * 32;
  int tx = threadIdx.x & 31, ty = threadIdx.x >> 5;
  const float* fp = fd + (size_t)bb*NC*NL;
  const float* bp = bd + (size_t)bb*NC*NL;
  #pragma unroll
  for (int r = 0; r < 32; r += 8) {
    tf[r + ty][tx] = fp[(size_t)(c0 + r + ty)*NL + p0 + tx];
    tb[r + ty][tx] = bp[(size_t)(c0 + r + ty)*NL + p0 + tx];
  }
  __syncthreads();
  #pragma unroll
  for (int r = 0; r < 32; r += 8) {
    float fv = tf[tx][r + ty];
    float bv = tb[tx][r + ty];
    size_t idx = ((size_t)bb*NL + p0 + r + ty)*NC + c0 + tx;
    fdt[idx] = f2bf(fv);
    bdt[idx] = f2bf(bv);
    fdp[idx] = fv;
    bdp[idx] = bv;
  }
}

// ---------- pixel-dot GEMM with fused horizontal stencil: writes E directly ----------
// E[p][l] = sum_dw bf16dot(p+dw, l+dw); all taps are tile-local (masks kill
// the cases that would cross 64-row boundaries). D never hits global memory.
__global__ __launch_bounds__(256) void k_gemmE(
    const unsigned short* __restrict__ A, const unsigned short* __restrict__ B,
    unsigned short* __restrict__ Eall, size_t eStride, int bbFixed) {
  __shared__ __align__(16) unsigned short Smem[128*DSTR];  // 34.8 KB; As/Bs union Ds
  unsigned short* As = Smem;            // 128*32 u16
  unsigned short* Bs = Smem + 128*32;
  unsigned short* Ds = Smem;
  int bb = (bbFixed >= 0) ? bbFixed : blockIdx.z;
  const unsigned short* Abase = A + (size_t)bb*NL*NC;
  const unsigned short* Bbase = B + (size_t)bb*NL*NC;
  unsigned short* E = Eall + (size_t)(bbFixed >= 0 ? 0 : bb) * eStride;
  int t = threadIdx.x;
  int w = t >> 6, l = t & 63;
  int by = blockIdx.y, bx = blockIdx.x;
  int wr = w >> 1, wc = w & 1;
  f32x4 acc[4][4] = {};
  int aoff[4], boff[4];
  #pragma unroll
  for (int m = 0; m < 4; ++m) {
    aoff[m] = ((wr*64 + m*16 + (l & 15)) * 32 + ((l >> 4) * 8)) * 2;
    boff[m] = ((wc*64 + m*16 + (l & 15)) * 32 + ((l >> 4) * 8)) * 2;
  }
  const char* Ab = (const char*)Abase;
  const char* Bb = (const char*)Bbase;
  char* AsB = (char*)As;
  char* BsB = (char*)Bs;
  int off = (w*2) * 1024 + l * 16;
  int r0i = off >> 6, cb0 = off & 63;
  int off1 = off + 1024;
  int r1i = off1 >> 6, cb1 = off1 & 63;
  for (int k0 = 0; k0 < 128; k0 += 32) {
    gload_lds16(Ab + ((size_t)(by*128 + r0i) * 128 + k0) * 2 + cb0, AsB + (w*2+0)*1024);
    gload_lds16(Ab + ((size_t)(by*128 + r1i) * 128 + k0) * 2 + cb1, AsB + (w*2+1)*1024);
    gload_lds16(Bb + ((size_t)(bx*128 + r0i) * 128 + k0) * 2 + cb0, BsB + (w*2+0)*1024);
    gload_lds16(Bb + ((size_t)(bx*128 + r1i) * 128 + k0) * 2 + cb1, BsB + (w*2+1)*1024);
    __syncthreads();
    s16x8 af[4], bf[4];
    #pragma unroll
    for (int m = 0; m < 4; ++m) af[m] = *(const s16x8*)(AsB + aoff[m]);
    #pragma unroll
    for (int n = 0; n < 4; ++n) bf[n] = *(const s16x8*)(BsB + boff[n]);
    #pragma unroll
    for (int m = 0; m < 4; ++m)
      #pragma unroll
      for (int n = 0; n < 4; ++n)
        acc[m][n] = __builtin_amdgcn_mfma_f32_16x16x32_bf16(af[m], bf[n], acc[m][n], 0, 0, 0);
    __syncthreads();
  }
  // write acc tile as bf16 into Ds (As/Bs dead after last barrier)
  int cr = l >> 4;
  int cc = l & 15;
  #pragma unroll
  for (int n = 0; n < 4; ++n) {
    int col = wc*64 + n*16 + cc;
    #pragma unroll
    for (int m = 0; m < 4; ++m) {
      int row = wr*64 + m*16 + cr*4;
      #pragma unroll
      for (int j = 0; j < 4; ++j)
        Ds[(row + j)*DSTR + col] = f2bf(acc[m][n][j]);
    }
  }
  __syncthreads();
  // horizontal stencil from LDS, coalesced uint4 E stores
  #pragma unroll
  for (int rr = 0; rr < 8; ++rr) {
    int r = (t >> 4) + rr*16;
    int cb = (t & 15) * 8;
    bool okm = (r & 63) > 0;
    bool okp = (r & 63) < 63;
    const unsigned short* rowc = Ds + r*DSTR;
    uint4 cen = *(const uint4*)(rowc + cb);
    uint4 bm4 = okm ? *(const uint4*)(rowc - DSTR + cb) : make_uint4(0,0,0,0);
    uint4 bp4 = okp ? *(const uint4*)(rowc + DSTR + cb) : make_uint4(0,0,0,0);
    unsigned amw = (okm && (cb & 63) != 0)  ? *(const unsigned*)(rowc - DSTR + cb - 2) : 0u;
    unsigned cpx = (okp && (cb & 63) != 56) ? *(const unsigned*)(rowc + DSTR + cb + 8) : 0u;
    unsigned b0u[4] = {cen.x, cen.y, cen.z, cen.w};
    unsigned bmu[4] = {bm4.x, bm4.y, bm4.z, bm4.w};
    unsigned bpu[4] = {bp4.x, bp4.y, bp4.z, bp4.w};
    unsigned sm[4], sp[4];
    sm[0] = (amw >> 16)    | (bmu[0] << 16);
    sm[1] = (bmu[0] >> 16) | (bmu[1] << 16);
    sm[2] = (bmu[1] >> 16) | (bmu[2] << 16);
    sm[3] = (bmu[2] >> 16) | (bmu[3] << 16);
    sp[0] = (bpu[0] >> 16) | (bpu[1] << 16);
    sp[1] = (bpu[1] >> 16) | (bpu[2] << 16);
    sp[2] = (bpu[2] >> 16) | (bpu[3] << 16);
    sp[3] = (bpu[3] >> 16) | (cpx << 16);
    unsigned eo[4];
    #pragma unroll
    for (int k = 0; k < 4; ++k) {
      int lx0 = (cb + 2*k) & 63;
      float v0 = (okm && lx0 > 0) ? bf2f((unsigned short)(sm[k] & 0xffffu)) : 0.f;
      v0 += bf2f((unsigned short)(b0u[k] & 0xffffu));
      v0 += (okp && lx0 < 63) ? bf2f((unsigned short)(sp[k] & 0xffffu)) : 0.f;
      int lx1 = (cb + 2*k + 1) & 63;
      float v1 = (okm && lx1 > 0) ? bf2f((unsigned short)(sm[k] >> 16)) : 0.f;
      v1 += bf2f((unsigned short)(b0u[k] >> 16));
      v1 += (okp && lx1 < 63) ? bf2f((unsigned short)(sp[k] >> 16)) : 0.f;
      eo[k] = (unsigned)f2bf(v0) | ((unsigned)f2bf(v1) << 16);
    }
    uint4 outv; outv.x = eo[0]; outv.y = eo[1]; outv.z = eo[2]; outv.w = eo[3];
    *(uint4*)(E + (size_t)(by*128 + r) * NL + bx*128 + cb) = outv;
  }
}

// ---------- wave-per-row: single-pass stencil + rowmax + collect + exact rescore ----------
__global__ __launch_bounds__(256) void k_rescore5(const unsigned short* __restrict__ Eall,
    size_t eStride, const float* __restrict__ rnm, const float* __restrict__ fdp,
    const float* __restrict__ bdp, const float* __restrict__ nrm,
    const int* __restrict__ zb, int* __restrict__ cnt, Ent* __restrict__ ent,
    float* __restrict__ ooff, int bbFixed) {
  __shared__ float fpat_s[4][1152];   // [r][c] per wave
  __shared__ int   cl_s[4][MAXC];
  __shared__ float cs_s[4][MAXC];
  __shared__ int   cnt_s[4];
  int bb = (bbFixed >= 0) ? bbFixed : blockIdx.y;
  const unsigned short* E = Eall + (size_t)(bbFixed >= 0 ? 0 : bb) * eStride;
  int t = threadIdx.x;
  int w = t >> 6, lane = t & 63;
  int p = blockIdx.x * 4 + w;
  int py = p >> 6;
  int ihp = py, iwp = p & 63;
  float* fpat = fpat_s[w];
  int* cl = cl_s[w];
  float* cs = cs_s[w];
  const float* fdpb = fdp + (size_t)bb*NL*NC;
  const float* bdpb = bdp + (size_t)bb*NL*NC;
  const float* rb = rnm + bb*NL;
  const float* nb = nrm + bb*NL;
  if (lane == 0) cnt_s[w] = 0;

  // stage fpat: 9 iterations of float2 (coalesced 512 B), layout [r*128+c]
  #pragma unroll
  for (int r = 0; r < 9; ++r) {
    int y = ihp + r/3 - 1, x = iwp + (r % 3) - 1;
    bool ok = ((unsigned)y < 64u) && ((unsigned)x < 64u);
    float2 v = ok ? *(const float2*)(fdpb + (size_t)(y*WD + x)*NC + lane*2)
                  : make_float2(0.f, 0.f);
    fpat[r*128 + lane*2]     = v.x;
    fpat[r*128 + lane*2 + 1] = v.y;
  }

  // single pass: compute s (fp32), track max, keep packed-bf16 copies in registers
  unsigned spk[8][4];
  float mx = -3e38f;
  #pragma unroll
  for (int j = 0; j < 8; ++j) {
    int cb = j*512 + lane*8;
    int ly = cb >> 6;
    bool okm = (py > 0) && (ly > 0);
    bool okp = (py < 63) && (ly < 63);
    size_t a0 = (size_t)p*NL + cb;
    uint4 e0 = *(const uint4*)(E + a0);
    uint4 em = *(const uint4*)(E + (okm ? ((size_t)(p-64)*NL + cb - 64) : a0));
    uint4 ep = *(const uint4*)(E + (okp ? ((size_t)(p+64)*NL + cb + 64) : a0));
    float4 r0 = *(const float4*)(rb + cb);
    float4 r1 = *(const float4*)(rb + cb + 4);
    unsigned e0u[4] = {e0.x,e0.y,e0.z,e0.w};
    unsigned emu[4] = {em.x,em.y,em.z,em.w};
    unsigned epu[4] = {ep.x,ep.y,ep.z,ep.w};
    float rr8[8] = {r0.x,r0.y,r0.z,r0.w,r1.x,r1.y,r1.z,r1.w};
    #pragma unroll
    for (int k = 0; k < 4; ++k) {
      float v0 = okm ? bf2f((unsigned short)(emu[k] & 0xffffu)) : 0.f;
      v0 += bf2f((unsigned short)(e0u[k] & 0xffffu));
      v0 += okp ? bf2f((unsigned short)(epu[k] & 0xffffu)) : 0.f;
      float v1 = okm ? bf2f((unsigned short)(emu[k] >> 16)) : 0.f;
      v1 += bf2f((unsigned short)(e0u[k] >> 16));
      v1 += okp ? bf2f((unsigned short)(epu[k] >> 16)) : 0.f;
      float s0 = v0 * rr8[2*k];          // NaN when masked
      float s1 = v1 * rr8[2*k+1];
      mx = fmaxf(mx, s0);                // fmaxf ignores NaN
      mx = fmaxf(mx, s1);
      spk[j][k] = (unsigned)f2bf(s0) | ((unsigned)f2bf(s1) << 16);
    }
  }
  #pragma unroll
  for (int o = 32; o > 0; o >>= 1) mx = fmaxf(mx, __shfl_xor(mx, o, 64));
  float thr = mx - CUTS;

  // collect candidates from registers (NaN >= thr is false)
  #pragma unroll
  for (int j = 0; j < 8; ++j) {
    int cb = j*512 + lane*8;
    #pragma unroll
    for (int k = 0; k < 4; ++k) {
      float s0 = bf2f((unsigned short)(spk[j][k] & 0xffffu));
      float s1 = bf2f((unsigned short)(spk[j][k] >> 16));
      if (s0 >= thr) {
        int slot = atomicAdd(&cnt_s[w], 1);
        if (slot < MAXC) cl[slot] = cb + 2*k;
      }
      if (s1 >= thr) {
        int slot = atomicAdd(&cnt_s[w], 1);
        if (slot < MAXC) cl[slot] = cb + 2*k + 1;
      }
    }
  }
  int nc = cnt_s[w];           // wave-synchronous: atomics complete within wave
  nc = __shfl(nc, 0, 64);
  nc = nc < MAXC ? nc : MAXC;
  if (lane == 0 && nc > 1) {   // deterministic order: sort candidates by l
    for (int a = 1; a < nc; ++a) {
      int v = cl[a]; int q = a - 1;
      while (q >= 0 && cl[q] > v) { cl[q+1] = cl[q]; --q; }
      cl[q+1] = v;
    }
  }
  // exact fp32 dot per candidate: lane = channel pair (coalesced float2)
  for (int a = 0; a < nc; ++a) {
    int lidx = cl[a];
    int ph = lidx >> 6, pw = lidx & 63;
    float sum = 0.f;
    #pragma unroll
    for (int r = 0; r < 9; ++r) {
      int y = ph + r/3 - 1, x = pw + (r % 3) - 1;
      bool ok = ((unsigned)y < 64u) && ((unsigned)x < 64u);
      const float* brow = bdpb + (size_t)(y*WD + x)*NC;
      float2 bv = ok ? *(const float2*)(brow + lane*2) : make_float2(0.f, 0.f);
      sum = fmaf(fpat[r*128 + lane*2],     bv.x, sum);
      sum = fmaf(fpat[r*128 + lane*2 + 1], bv.y, sum);
    }
    #pragma unroll
    for (int o = 32; o > 0; o >>= 1) sum += __shfl_xor(sum, o, 64);
    if (lane == 0) cs[a] = sum / fmaxf(nb[lidx], 1e-4f);
  }
  if (lane == 0) {
    float smax = -3e38f; int sidx = 0x7fffffff;
    for (int a = 0; a < nc; ++a)
      if (cs[a] > smax) { smax = cs[a]; sidx = cl[a]; }   // sorted by l
    int Z = zb[bb];
    size_t base = (size_t)(bb*NL + p) * MAXENT;
    if (nc == 0) {
      cnt[bb*NL + p] = 0;
      ooff[((bb*2 + 0)*HD + ihp)*WD + iwp] = (float)(0 - ihp);
      ooff[((bb*2 + 1)*HD + ihp)*WD + iwp] = (float)(0 - iwp);
    } else {
      float xm = smax * SM_SCALE;
      if (Z > 0) xm = fmaxf(xm, 0.f);
      float den = 0.f;
      for (int a = 0; a < nc; ++a) {
        float d = cs[a] * SM_SCALE - xm;
        if (d > -CUT) den += expf(d);
      }
      if (Z > 0 && -xm > -CUT) den += (float)Z * expf(-xm);
      int n = 0;
      for (int a = 0; a < nc && n < MAXENT; ++a) {
        float d = cs[a] * SM_SCALE - xm;
        if (d > -CUT) { ent[base + n].l = cl[a]; ent[base + n].p = expf(d) / den; ++n; }
      }
      cnt[bb*NL + p] = n;
      ooff[((bb*2 + 0)*HD + ihp)*WD + iwp] = (float)((sidx >> 6) - ihp);
      ooff[((bb*2 + 1)*HD + ihp)*WD + iwp] = (float)((sidx & 63) - iwp);
    }
  }
}

// ---------- gather v5: inline plan (8 pixels/block) + pixel-major bt gather ----------
__global__ __launch_bounds__(256) void k_gather5(const float* __restrict__ bt,
    const int* __restrict__ cnt, const Ent* __restrict__ ent,
    float* __restrict__ yout) {
  __shared__ float sm[8][132];
  __shared__ int   off_s[8][PLMAX];
  __shared__ float wt_s[8][PLMAX];
  __shared__ int   n_s[8];
  int bb = blockIdx.y;
  int pixbase = blockIdx.x * 8;
  int t = threadIdx.x;
  if (t < 8) {
    int pix = pixbase + t;
    int oh = pix >> 7, ow = pix & 127;
    int ihlo = (oh - 1) >> 1;
    int iwlo = (ow - 1) >> 1;
    int n = 0;
    #pragma unroll
    for (int a = 0; a < 2; ++a) {
      int ih = ihlo + a;
      if ((unsigned)ih >= 64u) continue;
      #pragma unroll
      for (int d = 0; d < 2; ++d) {
        int iw = iwlo + d;
        if ((unsigned)iw >= 64u) continue;
        int pidx = bb*NL + ih*WD + iw;
        int nn = cnt[pidx];
        const Ent* ep = ent + (size_t)pidx*MAXENT;
        for (int j = 0; j < nn; ++j) {
          Ent e = ep[j];
          int ph = e.l >> 6, pw = e.l & 63;
          int yy = oh + 2*(ph - ih);
          int xx = ow + 2*(pw - iw);
          if ((unsigned)yy < 128u && (unsigned)xx < 128u) {
            off_s[t][n] = yy*NW + xx;
            wt_s[t][n] = e.p;
            ++n;
          }
        }
      }
    }
    n_s[t] = n;
  }
  __syncthreads();
  int g = t & 31, pl = t >> 5;
  int c0 = g * 4;
  const float* btb = bt + (size_t)bb*NPIX*NC;
  int n = n_s[pl];
  float ax = 0.f, ay = 0.f, az = 0.f, aw = 0.f;
  for (int j = 0; j < n; ++j) {
    int off = off_s[pl][j];
    float wv = wt_s[pl][j];
    float4 v = *(const float4*)(btb + (size_t)off*NC + c0);
    ax = fmaf(wv, v.x, ax); ay = fmaf(wv, v.y, ay);
    az = fmaf(wv, v.z, az); aw = fmaf(wv, v.w, aw);
  }
  sm[pl][c0+0] = ax; sm[pl][c0+1] = ay; sm[pl][c0+2] = az; sm[pl][c0+3] = aw;
  __syncthreads();
  #pragma unroll
  for (int k = 0; k < 4; ++k) {
    int c = (t >> 3) + 32*k;
    int i = t & 7;
    yout[((size_t)bb*NC + c)*NPIX + pixbase + i] = sm[i][c] * 0.25f;
  }
}

extern "C" void kernel_launch(void* const* d_in, const int* in_sizes, int n_in,
                              void* d_out, int out_size, void* d_ws, size_t ws_size,
                              hipStream_t stream) {
  const float* f = (const float*)d_in[0];
  const float* b = (const float*)d_in[1];
  const float* mask = (const float*)d_in[2];
  float* out = (float*)d_out;

  char* w = (char*)d_ws;
  float* fd   = (float*)w;  w += (size_t)NB*NC*HD*WD*4;
  float* bd   = (float*)w;  w += (size_t)NB*NC*HD*WD*4;
  double* sq  = (double*)w; w += (size_t)NB*HD*WD*8;
  float* norm = (float*)w;  w += (size_t)NB*NL*4;
  float* rnm  = (float*)w;  w += (size_t)NB*NL*4;
  int* cnt    = (int*)w;    w += (size_t)NB*NL*4;
  Ent* ent    = (Ent*)w;    w += (size_t)NB*NL*MAXENT*sizeof(Ent);
  unsigned short* fdt = (unsigned short*)w; w += (size_t)NB*NL*NC*2;
  unsigned short* bdt = (unsigned short*)w; w += (size_t)NB*NL*NC*2;
  float* fdp  = (float*)w;  w += (size_t)NB*NL*NC*4;
  float* bdp  = (float*)w;  w += (size_t)NB*NL*NC*4;
  int* zb     = (int*)w;    w += 64;

  size_t eBytes = (size_t)NL*NL*2;          // one batch of E (33.55 MB)
  size_t usedSoFar = (size_t)(w - (char*)d_ws);
  bool batched = (ws_size >= usedSoFar + (size_t)NB*eBytes);

  unsigned short* E = (unsigned short*)w;   // bt aliases E (E consumed before btrans)
  float* bt = (float*)w;

  int n1 = NB*NC*HD*WD;
  k_prep<<<(n1+255)/256, 256, 0, stream>>>(f, b, fd, bd);
  k_sq<<<(NB*HD*WD+255)/256, 256, 0, stream>>>(bd, sq);
  hipMemsetAsync(zb, 0, 64, stream);
  k_normmm<<<(NB*NL+255)/256, 256, 0, stream>>>(sq, mask, norm, rnm, zb);
  k_fbtrans<<<dim3(NL/32, NC/32, NB), 256, 0, stream>>>(fd, bd, fdt, bdt, fdp, bdp);

  float* ooff = out + (size_t)NB*NC*NH*NW;
  if (batched) {
    k_gemmE<<<dim3(32, 32, NB), 256, 0, stream>>>(fdt, bdt, E, (size_t)NL*NL, -1);
    k_rescore5<<<dim3(NL/4, NB), 256, 0, stream>>>(E, (size_t)NL*NL, rnm, fdp, bdp,
                                                   norm, zb, cnt, ent, ooff, -1);
  } else {
    for (int bb = 0; bb < NB; ++bb) {
      k_gemmE<<<dim3(32, 32), 256, 0, stream>>>(fdt, bdt, E, 0, bb);
      k_rescore5<<<dim3(NL/4), 256, 0, stream>>>(E, 0, rnm, fdp, bdp,
                                                 norm, zb, cnt, ent, ooff, bb);
    }
  }
  k_btrans<<<dim3(NPIX/32, NC/32, NB), 256, 0, stream>>>(b, bt);
  k_gather5<<<dim3(NPIX/8, NB), 256, 0, stream>>>(bt, cnt, ent, out);
}

// Round 15
// 196.425 us; speedup vs baseline: 2.0622x; 1.0263x over previous
//
#include <hip/hip_runtime.h>
#include <cmath>

#define NB 4
#define NC 128
#define NH 128
#define NW 128
#define HD 64
#define WD 64
#define NL 4096      // 64*64 positions / patches
#define NPIX 16384   // 128*128 output pixels per batch
#define SM_SCALE 2550.0f
#define CUT 40.0f
#define CUTS 0.216f  // candidate margin in score units
#define MAXENT 8
#define MAXC 256
#define PLMAX 32     // 4 positions x MAXENT survivors
#define DSTR 136     // Ds LDS row stride (u16), 16B-aligned rows

struct Ent { int l; float p; };

typedef __attribute__((ext_vector_type(4))) float f32x4;
typedef __attribute__((ext_vector_type(8))) short s16x8;

__device__ __forceinline__ unsigned short f2bf(float x) {
  unsigned u = __float_as_uint(x);
  return (unsigned short)((u + 0x7fffu + ((u >> 16) & 1u)) >> 16);
}
__device__ __forceinline__ float bf2f(unsigned short h) {
  return __uint_as_float(((unsigned)h) << 16);
}
__device__ __forceinline__ void gload_lds16(const void* g, void* l) {
  __builtin_amdgcn_global_load_lds(
      (const __attribute__((address_space(1))) void*)g,
      (__attribute__((address_space(3))) void*)l, 16, 0, 0);
}

// ---------- prep ----------
__global__ void k_prep(const float* __restrict__ f, const float* __restrict__ b,
                       float* __restrict__ fd, float* __restrict__ bd) {
  int i = blockIdx.x * blockDim.x + threadIdx.x;
  if (i >= NB*NC*HD*WD) return;
  int x = i & 63, y = (i >> 6) & 63, c = (i >> 12) & 127, bb = i >> 19;
  int src = ((bb*NC + c)*NH + 2*y)*NW + 2*x;
  fd[i] = f[src];
  bd[i] = b[src];
}

__global__ void k_sq(const float* __restrict__ bd, double* __restrict__ sq) {
  int i = blockIdx.x * blockDim.x + threadIdx.x;
  if (i >= NB*HD*WD) return;
  int x = i & 63, y = (i >> 6) & 63, bb = i >> 12;
  double s = 0.0;
  const float* p = bd + (size_t)bb*NC*HD*WD + y*WD + x;
  for (int c = 0; c < NC; ++c) {
    double v = (double)p[(size_t)c*HD*WD];
    s += v*v;
  }
  sq[i] = s;
}

// norm, masked reciprocal (NaN when masked), zero-count
__global__ void k_normmm(const double* __restrict__ sq, const float* __restrict__ mask,
                         float* __restrict__ norm, float* __restrict__ rnm,
                         int* __restrict__ zb) {
  int i = blockIdx.x * blockDim.x + threadIdx.x;
  if (i >= NB*NL) return;
  int pw = i & 63, ph = (i >> 6) & 63, bb = i >> 12;
  double s = 0.0;
  for (int dh = -1; dh <= 1; ++dh) {
    int y = ph + dh; if ((unsigned)y >= 64u) continue;
    for (int dw = -1; dw <= 1; ++dw) {
      int x = pw + dw; if ((unsigned)x >= 64u) continue;
      s += sq[(bb*HD + y)*WD + x];
    }
  }
  float nv = (float)sqrt(s);
  norm[i] = nv;
  float ms = 0.f;
  const float* mb = mask + (size_t)bb*512*512;
  for (int dh = -1; dh <= 1; ++dh) {
    int y = ph + dh; if ((unsigned)y >= 64u) continue;
    for (int dw = -1; dw <= 1; ++dw) {
      int x = pw + dw; if ((unsigned)x >= 64u) continue;
      ms += mb[(y*8)*512 + x*8];
    }
  }
  bool unmasked = (ms == 0.f);
  rnm[i] = unmasked ? (1.f / fmaxf(nv, 1e-4f)) : __uint_as_float(0x7fc00000u);
  if (!unmasked) atomicAdd(&zb[bb], 1);
}

// ---------- transpose b to pixel-major b_t[bb][pix][c] (for gather) ----------
__global__ __launch_bounds__(256) void k_btrans(const float* __restrict__ b,
                                                float* __restrict__ bt) {
  __shared__ float tile[32][33];
  int bb = blockIdx.z;
  int c0 = blockIdx.y * 32;
  int p0 = blockIdx.x * 32;
  int tx = threadIdx.x & 31, ty = threadIdx.x >> 5;
  const float* bp = b + (size_t)bb*NC*NPIX;
  #pragma unroll
  for (int r = 0; r < 32; r += 8)
    tile[r + ty][tx] = bp[(size_t)(c0 + r + ty)*NPIX + p0 + tx];
  __syncthreads();
  float* btp = bt + (size_t)bb*NPIX*NC;
  #pragma unroll
  for (int r = 0; r < 32; r += 8)
    btp[(size_t)(p0 + r + ty)*NC + c0 + tx] = tile[tx][r + ty];
}

// ---------- transpose fd,bd to pixel-major: bf16 (GEMM) + fp32 (rescore) ----------
__global__ __launch_bounds__(256) void k_fbtrans(const float* __restrict__ fd,
    const float* __restrict__ bd, unsigned short* __restrict__ fdt,
    unsigned short* __restrict__ bdt, float* __restrict__ fdp,
    float* __restrict__ bdp) {
  __shared__ float tf[32][33], tb[32][33];
  int bb = blockIdx.z;
  int c0 = blockIdx.y * 32;
  int p0 = blockIdx.x * 32;
  int tx = threadIdx.x & 31, ty = threadIdx.x >> 5;
  const float* fp = fd + (size_t)bb*NC*NL;
  const float* bp = bd + (size_t)bb*NC*NL;
  #pragma unroll
  for (int r = 0; r < 32; r += 8) {
    tf[r + ty][tx] = fp[(size_t)(c0 + r + ty)*NL + p0 + tx];
    tb[r + ty][tx] = bp[(size_t)(c0 + r + ty)*NL + p0 + tx];
  }
  __syncthreads();
  #pragma unroll
  for (int r = 0; r < 32; r += 8) {
    float fv = tf[tx][r + ty];
    float bv = tb[tx][r + ty];
    size_t idx = ((size_t)bb*NL + p0 + r + ty)*NC + c0 + tx;
    fdt[idx] = f2bf(fv);
    bdt[idx] = f2bf(bv);
    fdp[idx] = fv;
    bdp[idx] = bv;
  }
}

// ---------- pixel-dot GEMM with fused horizontal stencil: writes E directly ----------
__global__ __launch_bounds__(256) void k_gemmE(
    const unsigned short* __restrict__ A, const unsigned short* __restrict__ B,
    unsigned short* __restrict__ Eall, size_t eStride, int bbFixed) {
  __shared__ __align__(16) unsigned short Smem[128*DSTR];  // 34.8 KB; As/Bs union Ds
  unsigned short* As = Smem;            // 128*32 u16
  unsigned short* Bs = Smem + 128*32;
  unsigned short* Ds = Smem;
  int bb = (bbFixed >= 0) ? bbFixed : blockIdx.z;
  const unsigned short* Abase = A + (size_t)bb*NL*NC;
  const unsigned short* Bbase = B + (size_t)bb*NL*NC;
  unsigned short* E = Eall + (size_t)(bbFixed >= 0 ? 0 : bb) * eStride;
  int t = threadIdx.x;
  int w = t >> 6, l = t & 63;
  int by = blockIdx.y, bx = blockIdx.x;
  int wr = w >> 1, wc = w & 1;
  f32x4 acc[4][4] = {};
  int aoff[4], boff[4];
  #pragma unroll
  for (int m = 0; m < 4; ++m) {
    aoff[m] = ((wr*64 + m*16 + (l & 15)) * 32 + ((l >> 4) * 8)) * 2;
    boff[m] = ((wc*64 + m*16 + (l & 15)) * 32 + ((l >> 4) * 8)) * 2;
  }
  const char* Ab = (const char*)Abase;
  const char* Bb = (const char*)Bbase;
  char* AsB = (char*)As;
  char* BsB = (char*)Bs;
  int off = (w*2) * 1024 + l * 16;
  int r0i = off >> 6, cb0 = off & 63;
  int off1 = off + 1024;
  int r1i = off1 >> 6, cb1 = off1 & 63;
  for (int k0 = 0; k0 < 128; k0 += 32) {
    gload_lds16(Ab + ((size_t)(by*128 + r0i) * 128 + k0) * 2 + cb0, AsB + (w*2+0)*1024);
    gload_lds16(Ab + ((size_t)(by*128 + r1i) * 128 + k0) * 2 + cb1, AsB + (w*2+1)*1024);
    gload_lds16(Bb + ((size_t)(bx*128 + r0i) * 128 + k0) * 2 + cb0, BsB + (w*2+0)*1024);
    gload_lds16(Bb + ((size_t)(bx*128 + r1i) * 128 + k0) * 2 + cb1, BsB + (w*2+1)*1024);
    __syncthreads();
    s16x8 af[4], bf[4];
    #pragma unroll
    for (int m = 0; m < 4; ++m) af[m] = *(const s16x8*)(AsB + aoff[m]);
    #pragma unroll
    for (int n = 0; n < 4; ++n) bf[n] = *(const s16x8*)(BsB + boff[n]);
    #pragma unroll
    for (int m = 0; m < 4; ++m)
      #pragma unroll
      for (int n = 0; n < 4; ++n)
        acc[m][n] = __builtin_amdgcn_mfma_f32_16x16x32_bf16(af[m], bf[n], acc[m][n], 0, 0, 0);
    __syncthreads();
  }
  int cr = l >> 4;
  int cc = l & 15;
  #pragma unroll
  for (int n = 0; n < 4; ++n) {
    int col = wc*64 + n*16 + cc;
    #pragma unroll
    for (int m = 0; m < 4; ++m) {
      int row = wr*64 + m*16 + cr*4;
      #pragma unroll
      for (int j = 0; j < 4; ++j)
        Ds[(row + j)*DSTR + col] = f2bf(acc[m][n][j]);
    }
  }
  __syncthreads();
  #pragma unroll
  for (int rr = 0; rr < 8; ++rr) {
    int r = (t >> 4) + rr*16;
    int cb = (t & 15) * 8;
    bool okm = (r & 63) > 0;
    bool okp = (r & 63) < 63;
    const unsigned short* rowc = Ds + r*DSTR;
    uint4 cen = *(const uint4*)(rowc + cb);
    uint4 bm4 = okm ? *(const uint4*)(rowc - DSTR + cb) : make_uint4(0,0,0,0);
    uint4 bp4 = okp ? *(const uint4*)(rowc + DSTR + cb) : make_uint4(0,0,0,0);
    unsigned amw = (okm && (cb & 63) != 0)  ? *(const unsigned*)(rowc - DSTR + cb - 2) : 0u;
    unsigned cpx = (okp && (cb & 63) != 56) ? *(const unsigned*)(rowc + DSTR + cb + 8) : 0u;
    unsigned b0u[4] = {cen.x, cen.y, cen.z, cen.w};
    unsigned bmu[4] = {bm4.x, bm4.y, bm4.z, bm4.w};
    unsigned bpu[4] = {bp4.x, bp4.y, bp4.z, bp4.w};
    unsigned sm[4], sp[4];
    sm[0] = (amw >> 16)    | (bmu[0] << 16);
    sm[1] = (bmu[0] >> 16) | (bmu[1] << 16);
    sm[2] = (bmu[1] >> 16) | (bmu[2] << 16);
    sm[3] = (bmu[2] >> 16) | (bmu[3] << 16);
    sp[0] = (bpu[0] >> 16) | (bpu[1] << 16);
    sp[1] = (bpu[1] >> 16) | (bpu[2] << 16);
    sp[2] = (bpu[2] >> 16) | (bpu[3] << 16);
    sp[3] = (bpu[3] >> 16) | (cpx << 16);
    unsigned eo[4];
    #pragma unroll
    for (int k = 0; k < 4; ++k) {
      int lx0 = (cb + 2*k) & 63;
      float v0 = (okm && lx0 > 0) ? bf2f((unsigned short)(sm[k] & 0xffffu)) : 0.f;
      v0 += bf2f((unsigned short)(b0u[k] & 0xffffu));
      v0 += (okp && lx0 < 63) ? bf2f((unsigned short)(sp[k] & 0xffffu)) : 0.f;
      int lx1 = (cb + 2*k + 1) & 63;
      float v1 = (okm && lx1 > 0) ? bf2f((unsigned short)(sm[k] >> 16)) : 0.f;
      v1 += bf2f((unsigned short)(b0u[k] >> 16));
      v1 += (okp && lx1 < 63) ? bf2f((unsigned short)(sp[k] >> 16)) : 0.f;
      eo[k] = (unsigned)f2bf(v0) | ((unsigned)f2bf(v1) << 16);
    }
    uint4 outv; outv.x = eo[0]; outv.y = eo[1]; outv.z = eo[2]; outv.w = eo[3];
    *(uint4*)(E + (size_t)(by*128 + r) * NL + bx*128 + cb) = outv;
  }
}

// ---------- wave-per-row rescore: fpat in REGISTERS (lane = channel pair) ----------
// LDS only for candidate lists -> ~8.5 KB/block -> high occupancy.
__global__ __launch_bounds__(256) void k_rescore5(const unsigned short* __restrict__ Eall,
    size_t eStride, const float* __restrict__ rnm, const float* __restrict__ fdp,
    const float* __restrict__ bdp, const float* __restrict__ nrm,
    const int* __restrict__ zb, int* __restrict__ cnt, Ent* __restrict__ ent,
    float* __restrict__ ooff, int bbFixed) {
  __shared__ int   cl_s[4][MAXC];
  __shared__ float cs_s[4][MAXC];
  __shared__ int   cnt_s[4];
  int bb = (bbFixed >= 0) ? bbFixed : blockIdx.y;
  const unsigned short* E = Eall + (size_t)(bbFixed >= 0 ? 0 : bb) * eStride;
  int t = threadIdx.x;
  int w = t >> 6, lane = t & 63;
  int p = blockIdx.x * 4 + w;
  int py = p >> 6;
  int ihp = py, iwp = p & 63;
  int* cl = cl_s[w];
  float* cs = cs_s[w];
  const float* fdpb = fdp + (size_t)bb*NL*NC;
  const float* bdpb = bdp + (size_t)bb*NL*NC;
  const float* rb = rnm + bb*NL;
  const float* nb = nrm + bb*NL;
  if (lane == 0) cnt_s[w] = 0;

  // fpat in registers: lane owns channels {2*lane, 2*lane+1} for each of 9 taps
  float fpat[18];
  #pragma unroll
  for (int r = 0; r < 9; ++r) {
    int y = ihp + r/3 - 1, x = iwp + (r % 3) - 1;
    bool ok = ((unsigned)y < 64u) && ((unsigned)x < 64u);
    float2 v = ok ? *(const float2*)(fdpb + (size_t)(y*WD + x)*NC + lane*2)
                  : make_float2(0.f, 0.f);
    fpat[2*r]     = v.x;
    fpat[2*r + 1] = v.y;
  }

  // single pass: compute s (fp32), track max, keep packed-bf16 copies in registers
  unsigned spk[8][4];
  float mx = -3e38f;
  #pragma unroll
  for (int j = 0; j < 8; ++j) {
    int cb = j*512 + lane*8;
    int ly = cb >> 6;
    bool okm = (py > 0) && (ly > 0);
    bool okp = (py < 63) && (ly < 63);
    size_t a0 = (size_t)p*NL + cb;
    uint4 e0 = *(const uint4*)(E + a0);
    uint4 em = *(const uint4*)(E + (okm ? ((size_t)(p-64)*NL + cb - 64) : a0));
    uint4 ep = *(const uint4*)(E + (okp ? ((size_t)(p+64)*NL + cb + 64) : a0));
    float4 r0 = *(const float4*)(rb + cb);
    float4 r1 = *(const float4*)(rb + cb + 4);
    unsigned e0u[4] = {e0.x,e0.y,e0.z,e0.w};
    unsigned emu[4] = {em.x,em.y,em.z,em.w};
    unsigned epu[4] = {ep.x,ep.y,ep.z,ep.w};
    float rr8[8] = {r0.x,r0.y,r0.z,r0.w,r1.x,r1.y,r1.z,r1.w};
    #pragma unroll
    for (int k = 0; k < 4; ++k) {
      float v0 = okm ? bf2f((unsigned short)(emu[k] & 0xffffu)) : 0.f;
      v0 += bf2f((unsigned short)(e0u[k] & 0xffffu));
      v0 += okp ? bf2f((unsigned short)(epu[k] & 0xffffu)) : 0.f;
      float v1 = okm ? bf2f((unsigned short)(emu[k] >> 16)) : 0.f;
      v1 += bf2f((unsigned short)(e0u[k] >> 16));
      v1 += okp ? bf2f((unsigned short)(epu[k] >> 16)) : 0.f;
      float s0 = v0 * rr8[2*k];          // NaN when masked
      float s1 = v1 * rr8[2*k+1];
      mx = fmaxf(mx, s0);                // fmaxf ignores NaN
      mx = fmaxf(mx, s1);
      spk[j][k] = (unsigned)f2bf(s0) | ((unsigned)f2bf(s1) << 16);
    }
  }
  #pragma unroll
  for (int o = 32; o > 0; o >>= 1) mx = fmaxf(mx, __shfl_xor(mx, o, 64));
  float thr = mx - CUTS;

  // collect candidates from registers (NaN >= thr is false)
  #pragma unroll
  for (int j = 0; j < 8; ++j) {
    int cb = j*512 + lane*8;
    #pragma unroll
    for (int k = 0; k < 4; ++k) {
      float s0 = bf2f((unsigned short)(spk[j][k] & 0xffffu));
      float s1 = bf2f((unsigned short)(spk[j][k] >> 16));
      if (s0 >= thr) {
        int slot = atomicAdd(&cnt_s[w], 1);
        if (slot < MAXC) cl[slot] = cb + 2*k;
      }
      if (s1 >= thr) {
        int slot = atomicAdd(&cnt_s[w], 1);
        if (slot < MAXC) cl[slot] = cb + 2*k + 1;
      }
    }
  }
  int nc = cnt_s[w];           // wave-synchronous: atomics complete within wave
  nc = __shfl(nc, 0, 64);
  nc = nc < MAXC ? nc : MAXC;
  if (lane == 0 && nc > 1) {   // deterministic order: sort candidates by l
    for (int a = 1; a < nc; ++a) {
      int v = cl[a]; int q = a - 1;
      while (q >= 0 && cl[q] > v) { cl[q+1] = cl[q]; --q; }
      cl[q+1] = v;
    }
  }
  // exact fp32 dot per candidate: lane = channel pair (coalesced float2)
  for (int a = 0; a < nc; ++a) {
    int lidx = cl[a];
    int ph = lidx >> 6, pw = lidx & 63;
    float sum = 0.f;
    #pragma unroll
    for (int r = 0; r < 9; ++r) {
      int y = ph + r/3 - 1, x = pw + (r % 3) - 1;
      bool ok = ((unsigned)y < 64u) && ((unsigned)x < 64u);
      const float* brow = bdpb + (size_t)(y*WD + x)*NC;
      float2 bv = ok ? *(const float2*)(brow + lane*2) : make_float2(0.f, 0.f);
      sum = fmaf(fpat[2*r],     bv.x, sum);
      sum = fmaf(fpat[2*r + 1], bv.y, sum);
    }
    #pragma unroll
    for (int o = 32; o > 0; o >>= 1) sum += __shfl_xor(sum, o, 64);
    if (lane == 0) cs[a] = sum / fmaxf(nb[lidx], 1e-4f);
  }
  if (lane == 0) {
    float smax = -3e38f; int sidx = 0x7fffffff;
    for (int a = 0; a < nc; ++a)
      if (cs[a] > smax) { smax = cs[a]; sidx = cl[a]; }   // sorted by l
    int Z = zb[bb];
    size_t base = (size_t)(bb*NL + p) * MAXENT;
    if (nc == 0) {
      cnt[bb*NL + p] = 0;
      ooff[((bb*2 + 0)*HD + ihp)*WD + iwp] = (float)(0 - ihp);
      ooff[((bb*2 + 1)*HD + ihp)*WD + iwp] = (float)(0 - iwp);
    } else {
      float xm = smax * SM_SCALE;
      if (Z > 0) xm = fmaxf(xm, 0.f);
      float den = 0.f;
      for (int a = 0; a < nc; ++a) {
        float d = cs[a] * SM_SCALE - xm;
        if (d > -CUT) den += expf(d);
      }
      if (Z > 0 && -xm > -CUT) den += (float)Z * expf(-xm);
      int n = 0;
      for (int a = 0; a < nc && n < MAXENT; ++a) {
        float d = cs[a] * SM_SCALE - xm;
        if (d > -CUT) { ent[base + n].l = cl[a]; ent[base + n].p = expf(d) / den; ++n; }
      }
      cnt[bb*NL + p] = n;
      ooff[((bb*2 + 0)*HD + ihp)*WD + iwp] = (float)((sidx >> 6) - ihp);
      ooff[((bb*2 + 1)*HD + ihp)*WD + iwp] = (float)((sidx & 63) - iwp);
    }
  }
}

// ---------- gather v5: inline plan (8 pixels/block) + pixel-major bt gather ----------
__global__ __launch_bounds__(256) void k_gather5(const float* __restrict__ bt,
    const int* __restrict__ cnt, const Ent* __restrict__ ent,
    float* __restrict__ yout) {
  __shared__ float sm[8][132];
  __shared__ int   off_s[8][PLMAX];
  __shared__ float wt_s[8][PLMAX];
  __shared__ int   n_s[8];
  int bb = blockIdx.y;
  int pixbase = blockIdx.x * 8;
  int t = threadIdx.x;
  if (t < 8) {
    int pix = pixbase + t;
    int oh = pix >> 7, ow = pix & 127;
    int ihlo = (oh - 1) >> 1;
    int iwlo = (ow - 1) >> 1;
    int n = 0;
    #pragma unroll
    for (int a = 0; a < 2; ++a) {
      int ih = ihlo + a;
      if ((unsigned)ih >= 64u) continue;
      #pragma unroll
      for (int d = 0; d < 2; ++d) {
        int iw = iwlo + d;
        if ((unsigned)iw >= 64u) continue;
        int pidx = bb*NL + ih*WD + iw;
        int nn = cnt[pidx];
        const Ent* ep = ent + (size_t)pidx*MAXENT;
        for (int j = 0; j < nn; ++j) {
          Ent e = ep[j];
          int ph = e.l >> 6, pw = e.l & 63;
          int yy = oh + 2*(ph - ih);
          int xx = ow + 2*(pw - iw);
          if ((unsigned)yy < 128u && (unsigned)xx < 128u) {
            off_s[t][n] = yy*NW + xx;
            wt_s[t][n] = e.p;
            ++n;
          }
        }
      }
    }
    n_s[t] = n;
  }
  __syncthreads();
  int g = t & 31, pl = t >> 5;
  int c0 = g * 4;
  const float* btb = bt + (size_t)bb*NPIX*NC;
  int n = n_s[pl];
  float ax = 0.f, ay = 0.f, az = 0.f, aw = 0.f;
  for (int j = 0; j < n; ++j) {
    int off = off_s[pl][j];
    float wv = wt_s[pl][j];
    float4 v = *(const float4*)(btb + (size_t)off*NC + c0);
    ax = fmaf(wv, v.x, ax); ay = fmaf(wv, v.y, ay);
    az = fmaf(wv, v.z, az); aw = fmaf(wv, v.w, aw);
  }
  sm[pl][c0+0] = ax; sm[pl][c0+1] = ay; sm[pl][c0+2] = az; sm[pl][c0+3] = aw;
  __syncthreads();
  #pragma unroll
  for (int k = 0; k < 4; ++k) {
    int c = (t >> 3) + 32*k;
    int i = t & 7;
    yout[((size_t)bb*NC + c)*NPIX + pixbase + i] = sm[i][c] * 0.25f;
  }
}

extern "C" void kernel_launch(void* const* d_in, const int* in_sizes, int n_in,
                              void* d_out, int out_size, void* d_ws, size_t ws_size,
                              hipStream_t stream) {
  const float* f = (const float*)d_in[0];
  const float* b = (const float*)d_in[1];
  const float* mask = (const float*)d_in[2];
  float* out = (float*)d_out;

  char* w = (char*)d_ws;
  float* fd   = (float*)w;  w += (size_t)NB*NC*HD*WD*4;
  float* bd   = (float*)w;  w += (size_t)NB*NC*HD*WD*4;
  double* sq  = (double*)w; w += (size_t)NB*HD*WD*8;
  float* norm = (float*)w;  w += (size_t)NB*NL*4;
  float* rnm  = (float*)w;  w += (size_t)NB*NL*4;
  int* cnt    = (int*)w;    w += (size_t)NB*NL*4;
  Ent* ent    = (Ent*)w;    w += (size_t)NB*NL*MAXENT*sizeof(Ent);
  unsigned short* fdt = (unsigned short*)w; w += (size_t)NB*NL*NC*2;
  unsigned short* bdt = (unsigned short*)w; w += (size_t)NB*NL*NC*2;
  float* fdp  = (float*)w;  w += (size_t)NB*NL*NC*4;
  float* bdp  = (float*)w;  w += (size_t)NB*NL*NC*4;
  int* zb     = (int*)w;    w += 64;

  size_t eBytes = (size_t)NL*NL*2;          // one batch of E (33.55 MB)
  size_t usedSoFar = (size_t)(w - (char*)d_ws);
  bool batched = (ws_size >= usedSoFar + (size_t)NB*eBytes);

  unsigned short* E = (unsigned short*)w;   // bt aliases E (E consumed before btrans)
  float* bt = (float*)w;

  int n1 = NB*NC*HD*WD;
  k_prep<<<(n1+255)/256, 256, 0, stream>>>(f, b, fd, bd);
  k_sq<<<(NB*HD*WD+255)/256, 256, 0, stream>>>(bd, sq);
  hipMemsetAsync(zb, 0, 64, stream);
  k_normmm<<<(NB*NL+255)/256, 256, 0, stream>>>(sq, mask, norm, rnm, zb);
  k_fbtrans<<<dim3(NL/32, NC/32, NB), 256, 0, stream>>>(fd, bd, fdt, bdt, fdp, bdp);

  float* ooff = out + (size_t)NB*NC*NH*NW;
  if (batched) {
    k_gemmE<<<dim3(32, 32, NB), 256, 0, stream>>>(fdt, bdt, E, (size_t)NL*NL, -1);
    k_rescore5<<<dim3(NL/4, NB), 256, 0, stream>>>(E, (size_t)NL*NL, rnm, fdp, bdp,
                                                   norm, zb, cnt, ent, ooff, -1);
  } else {
    for (int bb = 0; bb < NB; ++bb) {
      k_gemmE<<<dim3(32, 32), 256, 0, stream>>>(fdt, bdt, E, 0, bb);
      k_rescore5<<<dim3(NL/4), 256, 0, stream>>>(E, 0, rnm, fdp, bdp,
                                                 norm, zb, cnt, ent, ooff, bb);
    }
  }
  k_btrans<<<dim3(NPIX/32, NC/32, NB), 256, 0, stream>>>(b, bt);
  k_gather5<<<dim3(NPIX/8, NB), 256, 0, stream>>>(bt, cnt, ent, out);
}